// Round 2
// baseline (325.970 us; speedup 1.0000x reference)
//
#include <hip/hip_runtime.h>

#define H    64
#define F    256
#define NSEG 256
#define SCB  2048   // scan elements per block
#define MB   64     // qkv node rows per block
#define KC   64     // qkv K chunk
#define XPAD 72     // LDS row stride in shorts (64 + 8: 16B-aligned, 2-way-free)

typedef float          f32x4v __attribute__((ext_vector_type(4)));
typedef short          bf16x8 __attribute__((ext_vector_type(8)));
typedef unsigned short u16x4  __attribute__((ext_vector_type(4)));

// ---------------------------------------------------------------------------
// Kernel 0: transpose+split W (3 x [256,64] fp32) into Wt[mat*64+j][k] bf16
// hi/lo (truncation split: w = hi + lo + O(2^-17)).  192 blocks = (mat,j).
// ---------------------------------------------------------------------------
__global__ __launch_bounds__(256) void w_convert(
    const float* __restrict__ Wq, const float* __restrict__ Wk,
    const float* __restrict__ Wv,
    unsigned short* __restrict__ wt_hi, unsigned short* __restrict__ wt_lo)
{
    const int b   = blockIdx.x;        // mat*64 + j
    const int mat = b >> 6;
    const int j   = b & 63;
    const int t   = threadIdx.x;       // k
    const float* W = (mat == 0) ? Wq : (mat == 1) ? Wk : Wv;
    float f = W[t * H + j];
    unsigned u = __float_as_uint(f);
    unsigned short hi = (unsigned short)(u >> 16);
    float rf = f - __uint_as_float(u & 0xFFFF0000u);
    unsigned short lo = (unsigned short)(__float_as_uint(rf) >> 16);
    const size_t o = (size_t)b * F + t;
    wt_hi[o] = hi;
    wt_lo[o] = lo;
}

// ---------------------------------------------------------------------------
// In-degree histogram, STANDALONE (de-fused from the GEMM).  Rationale: fused
// with the x-streaming GEMM, the 51 MB stream evicted the count lines from L2
// so every atomic was an HBM-latency RMW and the first __syncthreads (vmcnt
// drain) gated all waves behind it (WRITE_SIZE showed ~23 MB of count-line
// write-backs).  Standalone, counts8 (1.6 MB) stays L2-resident.
// 8-way privatized, copy = blockIdx&7 == (e>>10)&7, matching reorder.
// ---------------------------------------------------------------------------
__global__ __launch_bounds__(256) void hist_kernel(
    const int* __restrict__ ei, int* __restrict__ counts8, int N, int E)
{
    const int pbase = (blockIdx.x & 7) * N;
    const int e0 = blockIdx.x * 1024 + threadIdx.x * 4;
    if (e0 + 3 < E) {
        const int4 d4 = *(const int4*)(ei + E + e0);
        atomicAdd(&counts8[pbase + min(max(d4.x, 0), N - 1)], 1);
        atomicAdd(&counts8[pbase + min(max(d4.y, 0), N - 1)], 1);
        atomicAdd(&counts8[pbase + min(max(d4.z, 0), N - 1)], 1);
        atomicAdd(&counts8[pbase + min(max(d4.w, 0), N - 1)], 1);
    } else {
        for (int e = e0; e < E; ++e) {
            int dst = ei[E + e];
            atomicAdd(&counts8[pbase + min(max(dst, 0), N - 1)], 1);
        }
    }
}

// ---------------------------------------------------------------------------
// Kernel 1: QKV via split-bf16 MFMA (atomics removed; pure GEMM now).
// Wave w owns output-column tile nt=w (16 cols); computes all 4 m-tiles x
// 3 mats.  Per K-chunk (64): stage x hi/lo in LDS (short4 writes), preload
// ALL B frags for the chunk into registers, then 72 MFMAs back-to-back.
//   acc += xh*wh + xh*wl + xl*wh    (xl*wl ~ 2^-17 dropped)
// ---------------------------------------------------------------------------
__global__ __launch_bounds__(256) void qkv_mfma(
    const float* __restrict__ x,
    const unsigned short* __restrict__ wt_hi,
    const unsigned short* __restrict__ wt_lo,
    const float* __restrict__ bq, const float* __restrict__ bk,
    const float* __restrict__ bv,
    float* __restrict__ q, float* __restrict__ k, float* __restrict__ v,
    int N)
{
    __shared__ unsigned short xs_hi[MB * XPAD];
    __shared__ unsigned short xs_lo[MB * XPAD];

    const int t = threadIdx.x;

    const int block0 = blockIdx.x * MB;
    const int rows = min(MB, N - block0);

    const int lane = t & 63;
    const int nt   = t >> 6;       // wave id = output col tile
    const int l15  = lane & 15;
    const int quad = lane >> 4;

    f32x4v acc[12];                // [mat*4 + mtile]
    #pragma unroll
    for (int i = 0; i < 12; ++i) acc[i] = (f32x4v)0.f;

    const size_t wbase = (size_t)(nt * 16 + l15) * F + quad * 8;

    for (int kb = 0; kb < F; kb += KC) {
        __syncthreads();                       // LDS reuse fence
        // --- stage x[block0..+64][kb..+64] as bf16 hi/lo, short4 writes ---
        #pragma unroll
        for (int it = 0; it < 4; ++it) {
            int idx = it * 256 + t;
            int r  = idx >> 4;                 // 16 float4 per row
            int c4 = idx & 15;
            float4 val = (r < rows)
                ? *(const float4*)(x + (size_t)(block0 + r) * F + kb + c4 * 4)
                : make_float4(0.f, 0.f, 0.f, 0.f);
            const float ff[4] = {val.x, val.y, val.z, val.w};
            u16x4 h, l;
            #pragma unroll
            for (int u = 0; u < 4; ++u) {
                unsigned ub = __float_as_uint(ff[u]);
                h[u] = (unsigned short)(ub >> 16);
                float rf = ff[u] - __uint_as_float(ub & 0xFFFF0000u);
                l[u] = (unsigned short)(__float_as_uint(rf) >> 16);
            }
            *(u16x4*)&xs_hi[r * XPAD + c4 * 4] = h;
            *(u16x4*)&xs_lo[r * XPAD + c4 * 4] = l;
        }
        __syncthreads();

        // --- preload ALL B frags for this chunk (independent loads) ---
        bf16x8 Bh[3][2], Bl[3][2];
        #pragma unroll
        for (int mat = 0; mat < 3; ++mat) {
            #pragma unroll
            for (int sk = 0; sk < 2; ++sk) {
                const size_t wo = wbase + (size_t)mat * 64 * F + kb + sk * 32;
                Bh[mat][sk] = *(const bf16x8*)(wt_hi + wo);
                Bl[mat][sk] = *(const bf16x8*)(wt_lo + wo);
            }
        }

        // --- MFMA burst: 2 subk x 4 mtiles x 3 mats x 3 split-terms ---
        #pragma unroll
        for (int sk = 0; sk < 2; ++sk) {
            #pragma unroll
            for (int mt = 0; mt < 4; ++mt) {
                const int ao = (mt * 16 + l15) * XPAD + sk * 32 + quad * 8;
                const bf16x8 ah = *(const bf16x8*)&xs_hi[ao];
                const bf16x8 al = *(const bf16x8*)&xs_lo[ao];
                #pragma unroll
                for (int mat = 0; mat < 3; ++mat) {
                    f32x4v a = acc[mat * 4 + mt];
                    a = __builtin_amdgcn_mfma_f32_16x16x32_bf16(ah, Bh[mat][sk], a, 0, 0, 0);
                    a = __builtin_amdgcn_mfma_f32_16x16x32_bf16(ah, Bl[mat][sk], a, 0, 0, 0);
                    a = __builtin_amdgcn_mfma_f32_16x16x32_bf16(al, Bh[mat][sk], a, 0, 0, 0);
                    acc[mat * 4 + mt] = a;
                }
            }
        }
    }

    // epilogue: C layout col = lane&15, row = quad*4 + reg  (m89-verified)
    float* outs[3] = {q, k, v};
    const float* biases[3] = {bq, bk, bv};
    const int col = nt * 16 + l15;
    #pragma unroll
    for (int mat = 0; mat < 3; ++mat) {
        float* dst = outs[mat];
        const float bb = biases[mat][col];
        #pragma unroll
        for (int mt = 0; mt < 4; ++mt) {
            #pragma unroll
            for (int r = 0; r < 4; ++r) {
                const int node = block0 + mt * 16 + quad * 4 + r;
                if (node < N)
                    dst[(size_t)node * H + col] = acc[mat * 4 + mt][r] + bb;
            }
        }
    }
}

// ---------------------------------------------------------------------------
// Scan phase A/B/C: exclusive scan of padded (x4) per-node total counts.
// scanA sums the 8 private histogram copies and emits the merged counts.
// scanC additionally carves each node's slot range into 8 disjoint per-copy
// sub-ranges (cursor8) so reorder can use privatized returning atomics.
// ---------------------------------------------------------------------------
__global__ __launch_bounds__(256) void scanA(
    const int* __restrict__ counts8, int* __restrict__ counts,
    int* __restrict__ offsets, int* __restrict__ bsum, int n)
{
    __shared__ int ps[256];
    const int t = threadIdx.x;
    const int i0 = blockIdx.x * SCB + t * 8;
    int loc[8];
    int s = 0;
    #pragma unroll
    for (int u = 0; u < 8; ++u) {
        int i = i0 + u;
        int c = 0;
        if (i < n) {
            #pragma unroll
            for (int p = 0; p < 8; ++p) c += counts8[p * n + i];
            counts[i] = c;
            c = (c + 3) & ~3;
        }
        loc[u] = s; s += c;
    }
    ps[t] = s;
    __syncthreads();
    for (int off = 1; off < 256; off <<= 1) {
        int a = (t >= off) ? ps[t - off] : 0;
        __syncthreads();
        ps[t] += a;
        __syncthreads();
    }
    const int base = ps[t] - s;
    #pragma unroll
    for (int u = 0; u < 8; ++u) {
        int i = i0 + u;
        if (i < n) offsets[i] = base + loc[u];
    }
    if (t == 255) bsum[blockIdx.x] = ps[255];
}

__global__ void scanB(int* __restrict__ bsum, int nb)
{
    // single-wave shuffle exclusive scan (nb <= 64)
    const int t = threadIdx.x;
    int v = (t < nb) ? bsum[t] : 0;
    int inc = v;
    #pragma unroll
    for (int off = 1; off < 64; off <<= 1) {
        int u = __shfl_up(inc, off, 64);
        if (t >= off) inc += u;
    }
    if (t < nb) bsum[t] = inc - v;   // exclusive
}

__global__ __launch_bounds__(256) void scanC(
    const int* __restrict__ bsum, const int* __restrict__ counts8,
    int* __restrict__ offsets, int* __restrict__ cursor8, int n)
{
    const int i0 = blockIdx.x * SCB + threadIdx.x * 8;
    const int add = bsum[blockIdx.x];
    #pragma unroll
    for (int u = 0; u < 8; ++u) {
        int i = i0 + u;
        if (i < n) {
            int o = offsets[i] + add;
            offsets[i] = o;
            #pragma unroll
            for (int p = 0; p < 8; ++p) {
                cursor8[p * n + i] = o;       // start of copy p's sub-range
                o += counts8[p * n + i];
            }
        }
    }
}

// ---------------------------------------------------------------------------
// Reorder edges into dst-node order.  pack = src(16b) | seg(8b)<<16.
// Same 1024-edges-per-block shape as the histogram so the edge -> private
// copy mapping (p = (e>>10)&7 = blockIdx&7) matches counts8 exactly.
// ---------------------------------------------------------------------------
__global__ __launch_bounds__(256) void reorder_kernel(
    const int* __restrict__ ei, const int* __restrict__ batch,
    int* __restrict__ cursor8, unsigned* __restrict__ epack, int E, int N)
{
    const int pbase = (blockIdx.x & 7) * N;
    int e = blockIdx.x * 1024 + threadIdx.x;
    #pragma unroll
    for (int u = 0; u < 4; ++u) {
        if (e < E) {
            int src = ei[e];
            int dst = ei[E + e];
            src = min(max(src, 0), N - 1);
            dst = min(max(dst, 0), N - 1);
            int seg = batch[src];
            seg = min(max(seg, 0), NSEG - 1);
            int pos = atomicAdd(&cursor8[pbase + dst], 1);
            epack[pos] = (unsigned)src | ((unsigned)seg << 16);
        }
        e += 256;
    }
}

// ---------------------------------------------------------------------------
// Score: persistent grid, one wave per dst node; q[dst] in registers across
// its edges; 4 edges in flight (16-lane groups, float4 k gathers, 4-step
// shuffle reduce).  Per-block LDS denom histogram flushed once into the
// block's XCD-private denom copy.
// ---------------------------------------------------------------------------
__global__ __launch_bounds__(256) void score_kernel(
    const float* __restrict__ q, const float* __restrict__ k,
    const unsigned* __restrict__ epack,
    const int* __restrict__ offsets, const int* __restrict__ counts,
    float* __restrict__ exps, float* __restrict__ denom8, int N)
{
    __shared__ float sden[NSEG];
    const int t = threadIdx.x;
    sden[t] = 0.f;
    __syncthreads();

    const int lane16 = t & 15;
    const int grp    = (t >> 4) & 3;
    const int wave   = t >> 6;
    const int nwaves = gridDim.x * 4;

    const float4* q4 = (const float4*)q;
    const float4* k4 = (const float4*)k;

    for (int n = blockIdx.x * 4 + wave; n < N; n += nwaves) {
        const int off = offsets[n];
        const int cnt = counts[n];
        if (cnt == 0) continue;
        const float4 qv = q4[(size_t)n * 16 + lane16];
        for (int i = grp; i < cnt; i += 4) {
            const int pos = off + i;
            const unsigned p = epack[pos];
            const int src = p & 0xFFFF;
            const float4 kv = k4[(size_t)src * 16 + lane16];
            float d = kv.x * qv.x + kv.y * qv.y + kv.z * qv.z + kv.w * qv.w;
            d += __shfl_xor(d, 1, 64);
            d += __shfl_xor(d, 2, 64);
            d += __shfl_xor(d, 4, 64);
            d += __shfl_xor(d, 8, 64);
            if (lane16 == 0) {
                float ex = __expf(d * 0.125f);
                exps[pos] = ex;
                atomicAdd(&sden[(p >> 16) & 255], ex);
            }
        }
    }
    __syncthreads();
    float ds = sden[t];
    if (ds != 0.f) atomicAdd(&denom8[(blockIdx.x & 7) * NSEG + t], ds);
}

// ---------------------------------------------------------------------------
// Accumulate: one wave per dst node, lane = feature, register accumulator,
// zero atomics.  LDS reciprocal table built by summing the 8 denom copies.
// ---------------------------------------------------------------------------
__global__ __launch_bounds__(256) void accum_kernel(
    const float* __restrict__ v, const float* __restrict__ exps,
    const unsigned* __restrict__ epack,
    const int* __restrict__ offsets, const int* __restrict__ counts,
    const float* __restrict__ denom8, float* __restrict__ out, int N)
{
    __shared__ float rden[NSEG];
    const int t = threadIdx.x;
    {
        float dsum = 0.f;
        #pragma unroll
        for (int p = 0; p < 8; ++p) dsum += denom8[p * NSEG + t];
        rden[t] = 1.0f / (dsum + 1e-6f);
    }
    __syncthreads();

    const int lane = t & 63;
    const int wave = t >> 6;
    const int n = blockIdx.x * 4 + wave;
    if (n >= N) return;

    const int off = offsets[n];
    const int cnt = counts[n];

    float acc = 0.f;
    int i = 0;
    for (; i + 8 <= cnt; i += 8) {
        const uint4  pa = *(const uint4*)(epack + off + i);
        const uint4  pb = *(const uint4*)(epack + off + i + 4);
        const float4 ea = *(const float4*)(exps + off + i);
        const float4 eb = *(const float4*)(exps + off + i + 4);
        const float v0 = v[(size_t)(pa.x & 0xFFFF) * H + lane];
        const float v1 = v[(size_t)(pa.y & 0xFFFF) * H + lane];
        const float v2 = v[(size_t)(pa.z & 0xFFFF) * H + lane];
        const float v3 = v[(size_t)(pa.w & 0xFFFF) * H + lane];
        const float v4_ = v[(size_t)(pb.x & 0xFFFF) * H + lane];
        const float v5 = v[(size_t)(pb.y & 0xFFFF) * H + lane];
        const float v6 = v[(size_t)(pb.z & 0xFFFF) * H + lane];
        const float v7 = v[(size_t)(pb.w & 0xFFFF) * H + lane];
        acc = fmaf(v0, ea.x * rden[(pa.x >> 16) & 255], acc);
        acc = fmaf(v1, ea.y * rden[(pa.y >> 16) & 255], acc);
        acc = fmaf(v2, ea.z * rden[(pa.z >> 16) & 255], acc);
        acc = fmaf(v3, ea.w * rden[(pa.w >> 16) & 255], acc);
        acc = fmaf(v4_, eb.x * rden[(pb.x >> 16) & 255], acc);
        acc = fmaf(v5, eb.y * rden[(pb.y >> 16) & 255], acc);
        acc = fmaf(v6, eb.z * rden[(pb.z >> 16) & 255], acc);
        acc = fmaf(v7, eb.w * rden[(pb.w >> 16) & 255], acc);
    }
    for (; i + 4 <= cnt; i += 4) {
        const uint4  pp = *(const uint4*)(epack + off + i);
        const float4 ee = *(const float4*)(exps + off + i);
        const float v0 = v[(size_t)(pp.x & 0xFFFF) * H + lane];
        const float v1 = v[(size_t)(pp.y & 0xFFFF) * H + lane];
        const float v2 = v[(size_t)(pp.z & 0xFFFF) * H + lane];
        const float v3 = v[(size_t)(pp.w & 0xFFFF) * H + lane];
        acc = fmaf(v0, ee.x * rden[(pp.x >> 16) & 255], acc);
        acc = fmaf(v1, ee.y * rden[(pp.y >> 16) & 255], acc);
        acc = fmaf(v2, ee.z * rden[(pp.z >> 16) & 255], acc);
        acc = fmaf(v3, ee.w * rden[(pp.w >> 16) & 255], acc);
    }
    for (; i < cnt; ++i) {
        const unsigned p = epack[off + i];
        acc = fmaf(v[(size_t)(p & 0xFFFF) * H + lane],
                   exps[off + i] * rden[(p >> 16) & 255], acc);
    }
    out[(size_t)n * H + lane] = acc;
}

extern "C" void kernel_launch(void* const* d_in, const int* in_sizes, int n_in,
                              void* d_out, int out_size, void* d_ws, size_t ws_size,
                              hipStream_t stream)
{
    const float* x   = (const float*)d_in[0];
    const float* Wq  = (const float*)d_in[1];
    const float* bq  = (const float*)d_in[2];
    const float* Wk  = (const float*)d_in[3];
    const float* bk  = (const float*)d_in[4];
    const float* Wv  = (const float*)d_in[5];
    const float* bv  = (const float*)d_in[6];
    const int* ei    = (const int*)d_in[7];
    const int* batch = (const int*)d_in[8];

    const int N = in_sizes[8];        // 50000
    const int E = in_sizes[7] / 2;    // 800000
    const int EP = E + 3 * N + 16;    // padded edge-slot capacity

    float*    q       = (float*)d_ws;
    float*    k       = q + (size_t)N * H;
    float*    v       = k + (size_t)N * H;
    float*    exps    = v + (size_t)N * H;
    unsigned* epack   = (unsigned*)(exps + EP);
    int*      counts  = (int*)(epack + EP);
    int*      offsets = counts + N;
    int*      bsum    = offsets + N;
    float*    denom8  = (float*)(bsum + 64);
    unsigned short* wt_hi = (unsigned short*)(denom8 + 8 * NSEG);
    unsigned short* wt_lo = wt_hi + 3 * H * F;

    // Aliased scratch (lifetimes verified disjoint):
    //   counts8 (8N ints) lives in epack's slots: last read in scanC,
    //     epack first written in reorder.
    //   cursor8 (8N ints) lives in exps' slots: last touched in reorder,
    //     exps first written in score.
    int* counts8 = (int*)epack;
    int* cursor8 = (int*)exps;

    hipMemsetAsync(counts8, 0, 8 * (size_t)N * sizeof(int), stream);
    hipMemsetAsync(denom8, 0, 8 * NSEG * sizeof(float), stream);

    const int QB = (N + MB - 1) / MB;       // 782 row tiles
    const int EB = (E + 1023) / 1024;       // 782 edge chunks
    const int NBSC = (N + SCB - 1) / SCB;   // 25 scan blocks

    w_convert<<<3 * H, 256, 0, stream>>>(Wq, Wk, Wv, wt_hi, wt_lo);

    hist_kernel<<<EB, 256, 0, stream>>>(ei, counts8, N, E);

    qkv_mfma<<<QB, 256, 0, stream>>>(
        x, wt_hi, wt_lo, bq, bk, bv, q, k, v, N);

    scanA<<<NBSC, 256, 0, stream>>>(counts8, counts, offsets, bsum, N);
    scanB<<<1, 64, 0, stream>>>(bsum, NBSC);
    scanC<<<NBSC, 256, 0, stream>>>(bsum, counts8, offsets, cursor8, N);

    reorder_kernel<<<(E + 1023) / 1024, 256, 0, stream>>>(
        ei, batch, cursor8, epack, E, N);

    score_kernel<<<2048, 256, 0, stream>>>(
        q, k, epack, offsets, counts, exps, denom8, N);

    accum_kernel<<<(N + 3) / 4, 256, 0, stream>>>(
        v, exps, epack, offsets, counts, denom8, (float*)d_out, N);
}

// Round 3
// 315.685 us; speedup vs baseline: 1.0326x; 1.0326x over previous
//
#include <hip/hip_runtime.h>

#define H    64
#define F    256
#define NSEG 256
#define SCB  2048   // scan elements per block
#define MB   64     // qkv node rows per block
#define KC   64     // qkv K chunk
#define XPAD 72     // LDS row stride in shorts (64 + 8: 16B-aligned, 2-way-free)

typedef float          f32x4v __attribute__((ext_vector_type(4)));
typedef short          bf16x8 __attribute__((ext_vector_type(8)));
typedef unsigned short u16x4  __attribute__((ext_vector_type(4)));

// ---------------------------------------------------------------------------
// Kernel 0: transpose+split W (3 x [256,64] fp32) into Wt[mat*64+j][k] bf16
// hi/lo (truncation split: w = hi + lo + O(2^-17)).  192 blocks = (mat,j).
// ---------------------------------------------------------------------------
__global__ __launch_bounds__(256) void w_convert(
    const float* __restrict__ Wq, const float* __restrict__ Wk,
    const float* __restrict__ Wv,
    unsigned short* __restrict__ wt_hi, unsigned short* __restrict__ wt_lo)
{
    const int b   = blockIdx.x;        // mat*64 + j
    const int mat = b >> 6;
    const int j   = b & 63;
    const int t   = threadIdx.x;       // k
    const float* W = (mat == 0) ? Wq : (mat == 1) ? Wk : Wv;
    float f = W[t * H + j];
    unsigned u = __float_as_uint(f);
    unsigned short hi = (unsigned short)(u >> 16);
    float rf = f - __uint_as_float(u & 0xFFFF0000u);
    unsigned short lo = (unsigned short)(__float_as_uint(rf) >> 16);
    const size_t o = (size_t)b * F + t;
    wt_hi[o] = hi;
    wt_lo[o] = lo;
}

// ---------------------------------------------------------------------------
// In-degree histogram, standalone (counts8 1.6 MB stays L2-resident).
// 8-way privatized, copy = blockIdx&7 == (e>>10)&7, matching reorder.
// ---------------------------------------------------------------------------
__global__ __launch_bounds__(256) void hist_kernel(
    const int* __restrict__ ei, int* __restrict__ counts8, int N, int E)
{
    const int pbase = (blockIdx.x & 7) * N;
    const int e0 = blockIdx.x * 1024 + threadIdx.x * 4;
    if (e0 + 3 < E) {
        const int4 d4 = *(const int4*)(ei + E + e0);
        atomicAdd(&counts8[pbase + min(max(d4.x, 0), N - 1)], 1);
        atomicAdd(&counts8[pbase + min(max(d4.y, 0), N - 1)], 1);
        atomicAdd(&counts8[pbase + min(max(d4.z, 0), N - 1)], 1);
        atomicAdd(&counts8[pbase + min(max(d4.w, 0), N - 1)], 1);
    } else {
        for (int e = e0; e < E; ++e) {
            int dst = ei[E + e];
            atomicAdd(&counts8[pbase + min(max(dst, 0), N - 1)], 1);
        }
    }
}

// ---------------------------------------------------------------------------
// Kernel 1: QKV via split-bf16 MFMA.  T14 async-STAGE split + double-buffered
// LDS: per K-chunk, issue next chunk's x-loads right after the barrier, run
// the current chunk's MFMAs while they fly, convert+ds_write into the other
// buffer at the end (vmcnt wait lands there).  ONE barrier per chunk.
//   acc += xh*wh + xh*wl + xl*wh    (xl*wl ~ 2^-17 dropped)
// ---------------------------------------------------------------------------
__global__ __launch_bounds__(256) void qkv_mfma(
    const float* __restrict__ x,
    const unsigned short* __restrict__ wt_hi,
    const unsigned short* __restrict__ wt_lo,
    const float* __restrict__ bq, const float* __restrict__ bk,
    const float* __restrict__ bv,
    float* __restrict__ q, float* __restrict__ k, float* __restrict__ v,
    int N)
{
    __shared__ unsigned short xs_hi[2][MB * XPAD];   // 2 x 9216 B
    __shared__ unsigned short xs_lo[2][MB * XPAD];   // 2 x 9216 B

    const int t = threadIdx.x;
    const int block0 = blockIdx.x * MB;
    const int rows = min(MB, N - block0);

    const int sr = t >> 4;          // staging: row within 16-row stripe
    const int sc = t & 15;          // staging: float4 column

    const int lane = t & 63;
    const int nt   = t >> 6;        // wave id = output col tile
    const int l15  = lane & 15;
    const int quad = lane >> 4;

    f32x4v acc[12];                 // [mat*4 + mtile]
    #pragma unroll
    for (int i = 0; i < 12; ++i) acc[i] = (f32x4v)0.f;

    const size_t wbase = (size_t)(nt * 16 + l15) * F + quad * 8;

    // ---- prologue: load + convert + write chunk 0 into buffer 0 ----
    float4 vals[4];
    #pragma unroll
    for (int it = 0; it < 4; ++it) {
        const int rr = it * 16 + sr;
        vals[it] = (rr < rows)
            ? *(const float4*)(x + (size_t)(block0 + rr) * F + sc * 4)
            : make_float4(0.f, 0.f, 0.f, 0.f);
    }
    #pragma unroll
    for (int it = 0; it < 4; ++it) {
        const int rr = it * 16 + sr;
        const float ff[4] = {vals[it].x, vals[it].y, vals[it].z, vals[it].w};
        u16x4 h, l;
        #pragma unroll
        for (int u = 0; u < 4; ++u) {
            unsigned ub = __float_as_uint(ff[u]);
            h[u] = (unsigned short)(ub >> 16);
            float rf = ff[u] - __uint_as_float(ub & 0xFFFF0000u);
            l[u] = (unsigned short)(__float_as_uint(rf) >> 16);
        }
        *(u16x4*)&xs_hi[0][rr * XPAD + sc * 4] = h;
        *(u16x4*)&xs_lo[0][rr * XPAD + sc * 4] = l;
    }

    #pragma unroll 1
    for (int kb = 0; kb < F; kb += KC) {
        const int cur = (kb >> 6) & 1;
        __syncthreads();               // buf[cur] writes visible to all waves

        // --- issue next chunk's global loads EARLY (first use after MFMAs)
        if (kb + KC < F) {
            #pragma unroll
            for (int it = 0; it < 4; ++it) {
                const int rr = it * 16 + sr;
                vals[it] = (rr < rows)
                    ? *(const float4*)(x + (size_t)(block0 + rr) * F + (kb + KC) + sc * 4)
                    : make_float4(0.f, 0.f, 0.f, 0.f);
            }
        }

        // --- compute current chunk: per-sk B loads + 36 MFMAs each ---
        #pragma unroll
        for (int sk = 0; sk < 2; ++sk) {
            bf16x8 Bh[3], Bl[3];
            #pragma unroll
            for (int mat = 0; mat < 3; ++mat) {
                const size_t wo = wbase + (size_t)mat * 64 * F + kb + sk * 32;
                Bh[mat] = *(const bf16x8*)(wt_hi + wo);
                Bl[mat] = *(const bf16x8*)(wt_lo + wo);
            }
            #pragma unroll
            for (int mt = 0; mt < 4; ++mt) {
                const int ao = (mt * 16 + l15) * XPAD + sk * 32 + quad * 8;
                const bf16x8 ah = *(const bf16x8*)&xs_hi[cur][ao];
                const bf16x8 al = *(const bf16x8*)&xs_lo[cur][ao];
                #pragma unroll
                for (int mat = 0; mat < 3; ++mat) {
                    f32x4v a = acc[mat * 4 + mt];
                    a = __builtin_amdgcn_mfma_f32_16x16x32_bf16(ah, Bh[mat], a, 0, 0, 0);
                    a = __builtin_amdgcn_mfma_f32_16x16x32_bf16(ah, Bl[mat], a, 0, 0, 0);
                    a = __builtin_amdgcn_mfma_f32_16x16x32_bf16(al, Bh[mat], a, 0, 0, 0);
                    acc[mat * 4 + mt] = a;
                }
            }
        }

        // --- convert + write next chunk into the other buffer ---
        // (write-after-read safe: buf[nxt] last read in iter kb-1; all waves
        //  passed the top-of-kb barrier after those reads)
        if (kb + KC < F) {
            const int nxt = cur ^ 1;
            #pragma unroll
            for (int it = 0; it < 4; ++it) {
                const int rr = it * 16 + sr;
                const float ff[4] = {vals[it].x, vals[it].y, vals[it].z, vals[it].w};
                u16x4 h, l;
                #pragma unroll
                for (int u = 0; u < 4; ++u) {
                    unsigned ub = __float_as_uint(ff[u]);
                    h[u] = (unsigned short)(ub >> 16);
                    float rf = ff[u] - __uint_as_float(ub & 0xFFFF0000u);
                    l[u] = (unsigned short)(__float_as_uint(rf) >> 16);
                }
                *(u16x4*)&xs_hi[nxt][rr * XPAD + sc * 4] = h;
                *(u16x4*)&xs_lo[nxt][rr * XPAD + sc * 4] = l;
            }
        }
    }

    // epilogue: C layout col = lane&15, row = quad*4 + reg  (m89-verified)
    float* outs[3] = {q, k, v};
    const float* biases[3] = {bq, bk, bv};
    const int col = nt * 16 + l15;
    #pragma unroll
    for (int mat = 0; mat < 3; ++mat) {
        float* dst = outs[mat];
        const float bb = biases[mat][col];
        #pragma unroll
        for (int mt = 0; mt < 4; ++mt) {
            #pragma unroll
            for (int r = 0; r < 4; ++r) {
                const int node = block0 + mt * 16 + quad * 4 + r;
                if (node < N)
                    dst[(size_t)node * H + col] = acc[mat * 4 + mt][r] + bb;
            }
        }
    }
}

// ---------------------------------------------------------------------------
// Scan phase A/B/C: exclusive scan of padded (x4) per-node total counts.
// scanA sums the 8 private histogram copies and emits the merged counts.
// scanC additionally carves each node's slot range into 8 disjoint per-copy
// sub-ranges (cursor8) so reorder can use privatized returning atomics.
// ---------------------------------------------------------------------------
__global__ __launch_bounds__(256) void scanA(
    const int* __restrict__ counts8, int* __restrict__ counts,
    int* __restrict__ offsets, int* __restrict__ bsum, int n)
{
    __shared__ int ps[256];
    const int t = threadIdx.x;
    const int i0 = blockIdx.x * SCB + t * 8;
    int loc[8];
    int s = 0;
    #pragma unroll
    for (int u = 0; u < 8; ++u) {
        int i = i0 + u;
        int c = 0;
        if (i < n) {
            #pragma unroll
            for (int p = 0; p < 8; ++p) c += counts8[p * n + i];
            counts[i] = c;
            c = (c + 3) & ~3;
        }
        loc[u] = s; s += c;
    }
    ps[t] = s;
    __syncthreads();
    for (int off = 1; off < 256; off <<= 1) {
        int a = (t >= off) ? ps[t - off] : 0;
        __syncthreads();
        ps[t] += a;
        __syncthreads();
    }
    const int base = ps[t] - s;
    #pragma unroll
    for (int u = 0; u < 8; ++u) {
        int i = i0 + u;
        if (i < n) offsets[i] = base + loc[u];
    }
    if (t == 255) bsum[blockIdx.x] = ps[255];
}

__global__ void scanB(int* __restrict__ bsum, int nb)
{
    // single-wave shuffle exclusive scan (nb <= 64)
    const int t = threadIdx.x;
    int v = (t < nb) ? bsum[t] : 0;
    int inc = v;
    #pragma unroll
    for (int off = 1; off < 64; off <<= 1) {
        int u = __shfl_up(inc, off, 64);
        if (t >= off) inc += u;
    }
    if (t < nb) bsum[t] = inc - v;   // exclusive
}

__global__ __launch_bounds__(256) void scanC(
    const int* __restrict__ bsum, const int* __restrict__ counts8,
    int* __restrict__ offsets, int* __restrict__ cursor8, int n)
{
    const int i0 = blockIdx.x * SCB + threadIdx.x * 8;
    const int add = bsum[blockIdx.x];
    #pragma unroll
    for (int u = 0; u < 8; ++u) {
        int i = i0 + u;
        if (i < n) {
            int o = offsets[i] + add;
            offsets[i] = o;
            #pragma unroll
            for (int p = 0; p < 8; ++p) {
                cursor8[p * n + i] = o;       // start of copy p's sub-range
                o += counts8[p * n + i];
            }
        }
    }
}

// ---------------------------------------------------------------------------
// Reorder edges into dst-node order.  pack = src(16b) | seg(8b)<<16.
// Same 1024-edges-per-block shape as the histogram so the edge -> private
// copy mapping (p = (e>>10)&7 = blockIdx&7) matches counts8 exactly.
// ---------------------------------------------------------------------------
__global__ __launch_bounds__(256) void reorder_kernel(
    const int* __restrict__ ei, const int* __restrict__ batch,
    int* __restrict__ cursor8, unsigned* __restrict__ epack, int E, int N)
{
    const int pbase = (blockIdx.x & 7) * N;
    int e = blockIdx.x * 1024 + threadIdx.x;
    #pragma unroll
    for (int u = 0; u < 4; ++u) {
        if (e < E) {
            int src = ei[e];
            int dst = ei[E + e];
            src = min(max(src, 0), N - 1);
            dst = min(max(dst, 0), N - 1);
            int seg = batch[src];
            seg = min(max(seg, 0), NSEG - 1);
            int pos = atomicAdd(&cursor8[pbase + dst], 1);
            epack[pos] = (unsigned)src | ((unsigned)seg << 16);
        }
        e += 256;
    }
}

// ---------------------------------------------------------------------------
// Score: persistent grid, one wave per dst node; q[dst] in registers across
// its edges; 4 edges in flight (16-lane groups, float4 k gathers, 4-step
// shuffle reduce).  Per-block LDS denom histogram flushed once into the
// block's XCD-private denom copy.
// ---------------------------------------------------------------------------
__global__ __launch_bounds__(256) void score_kernel(
    const float* __restrict__ q, const float* __restrict__ k,
    const unsigned* __restrict__ epack,
    const int* __restrict__ offsets, const int* __restrict__ counts,
    float* __restrict__ exps, float* __restrict__ denom8, int N)
{
    __shared__ float sden[NSEG];
    const int t = threadIdx.x;
    sden[t] = 0.f;
    __syncthreads();

    const int lane16 = t & 15;
    const int grp    = (t >> 4) & 3;
    const int wave   = t >> 6;
    const int nwaves = gridDim.x * 4;

    const float4* q4 = (const float4*)q;
    const float4* k4 = (const float4*)k;

    for (int n = blockIdx.x * 4 + wave; n < N; n += nwaves) {
        const int off = offsets[n];
        const int cnt = counts[n];
        if (cnt == 0) continue;
        const float4 qv = q4[(size_t)n * 16 + lane16];
        for (int i = grp; i < cnt; i += 4) {
            const int pos = off + i;
            const unsigned p = epack[pos];
            const int src = p & 0xFFFF;
            const float4 kv = k4[(size_t)src * 16 + lane16];
            float d = kv.x * qv.x + kv.y * qv.y + kv.z * qv.z + kv.w * qv.w;
            d += __shfl_xor(d, 1, 64);
            d += __shfl_xor(d, 2, 64);
            d += __shfl_xor(d, 4, 64);
            d += __shfl_xor(d, 8, 64);
            if (lane16 == 0) {
                float ex = __expf(d * 0.125f);
                exps[pos] = ex;
                atomicAdd(&sden[(p >> 16) & 255], ex);
            }
        }
    }
    __syncthreads();
    float ds = sden[t];
    if (ds != 0.f) atomicAdd(&denom8[(blockIdx.x & 7) * NSEG + t], ds);
}

// ---------------------------------------------------------------------------
// Accumulate: one wave per dst node, lane = feature, register accumulator,
// zero atomics.  LDS reciprocal table built by summing the 8 denom copies.
// ---------------------------------------------------------------------------
__global__ __launch_bounds__(256) void accum_kernel(
    const float* __restrict__ v, const float* __restrict__ exps,
    const unsigned* __restrict__ epack,
    const int* __restrict__ offsets, const int* __restrict__ counts,
    const float* __restrict__ denom8, float* __restrict__ out, int N)
{
    __shared__ float rden[NSEG];
    const int t = threadIdx.x;
    {
        float dsum = 0.f;
        #pragma unroll
        for (int p = 0; p < 8; ++p) dsum += denom8[p * NSEG + t];
        rden[t] = 1.0f / (dsum + 1e-6f);
    }
    __syncthreads();

    const int lane = t & 63;
    const int wave = t >> 6;
    const int n = blockIdx.x * 4 + wave;
    if (n >= N) return;

    const int off = offsets[n];
    const int cnt = counts[n];

    float acc = 0.f;
    int i = 0;
    for (; i + 8 <= cnt; i += 8) {
        const uint4  pa = *(const uint4*)(epack + off + i);
        const uint4  pb = *(const uint4*)(epack + off + i + 4);
        const float4 ea = *(const float4*)(exps + off + i);
        const float4 eb = *(const float4*)(exps + off + i + 4);
        const float v0 = v[(size_t)(pa.x & 0xFFFF) * H + lane];
        const float v1 = v[(size_t)(pa.y & 0xFFFF) * H + lane];
        const float v2 = v[(size_t)(pa.z & 0xFFFF) * H + lane];
        const float v3 = v[(size_t)(pa.w & 0xFFFF) * H + lane];
        const float v4_ = v[(size_t)(pb.x & 0xFFFF) * H + lane];
        const float v5 = v[(size_t)(pb.y & 0xFFFF) * H + lane];
        const float v6 = v[(size_t)(pb.z & 0xFFFF) * H + lane];
        const float v7 = v[(size_t)(pb.w & 0xFFFF) * H + lane];
        acc = fmaf(v0, ea.x * rden[(pa.x >> 16) & 255], acc);
        acc = fmaf(v1, ea.y * rden[(pa.y >> 16) & 255], acc);
        acc = fmaf(v2, ea.z * rden[(pa.z >> 16) & 255], acc);
        acc = fmaf(v3, ea.w * rden[(pa.w >> 16) & 255], acc);
        acc = fmaf(v4_, eb.x * rden[(pb.x >> 16) & 255], acc);
        acc = fmaf(v5, eb.y * rden[(pb.y >> 16) & 255], acc);
        acc = fmaf(v6, eb.z * rden[(pb.z >> 16) & 255], acc);
        acc = fmaf(v7, eb.w * rden[(pb.w >> 16) & 255], acc);
    }
    for (; i + 4 <= cnt; i += 4) {
        const uint4  pp = *(const uint4*)(epack + off + i);
        const float4 ee = *(const float4*)(exps + off + i);
        const float v0 = v[(size_t)(pp.x & 0xFFFF) * H + lane];
        const float v1 = v[(size_t)(pp.y & 0xFFFF) * H + lane];
        const float v2 = v[(size_t)(pp.z & 0xFFFF) * H + lane];
        const float v3 = v[(size_t)(pp.w & 0xFFFF) * H + lane];
        acc = fmaf(v0, ee.x * rden[(pp.x >> 16) & 255], acc);
        acc = fmaf(v1, ee.y * rden[(pp.y >> 16) & 255], acc);
        acc = fmaf(v2, ee.z * rden[(pp.z >> 16) & 255], acc);
        acc = fmaf(v3, ee.w * rden[(pp.w >> 16) & 255], acc);
    }
    for (; i < cnt; ++i) {
        const unsigned p = epack[off + i];
        acc = fmaf(v[(size_t)(p & 0xFFFF) * H + lane],
                   exps[off + i] * rden[(p >> 16) & 255], acc);
    }
    out[(size_t)n * H + lane] = acc;
}

extern "C" void kernel_launch(void* const* d_in, const int* in_sizes, int n_in,
                              void* d_out, int out_size, void* d_ws, size_t ws_size,
                              hipStream_t stream)
{
    const float* x   = (const float*)d_in[0];
    const float* Wq  = (const float*)d_in[1];
    const float* bq  = (const float*)d_in[2];
    const float* Wk  = (const float*)d_in[3];
    const float* bk  = (const float*)d_in[4];
    const float* Wv  = (const float*)d_in[5];
    const float* bv  = (const float*)d_in[6];
    const int* ei    = (const int*)d_in[7];
    const int* batch = (const int*)d_in[8];

    const int N = in_sizes[8];        // 50000
    const int E = in_sizes[7] / 2;    // 800000
    const int EP = E + 3 * N + 16;    // padded edge-slot capacity

    float*    q       = (float*)d_ws;
    float*    k       = q + (size_t)N * H;
    float*    v       = k + (size_t)N * H;
    float*    exps    = v + (size_t)N * H;
    unsigned* epack   = (unsigned*)(exps + EP);
    int*      counts  = (int*)(epack + EP);
    int*      offsets = counts + N;
    int*      bsum    = offsets + N;
    float*    denom8  = (float*)(bsum + 64);
    unsigned short* wt_hi = (unsigned short*)(denom8 + 8 * NSEG);
    unsigned short* wt_lo = wt_hi + 3 * H * F;

    // Aliased scratch (lifetimes verified disjoint):
    //   counts8 (8N ints) lives in epack's slots: last read in scanC,
    //     epack first written in reorder.
    //   cursor8 (8N ints) lives in exps' slots: last touched in reorder,
    //     exps first written in score.
    int* counts8 = (int*)epack;
    int* cursor8 = (int*)exps;

    hipMemsetAsync(counts8, 0, 8 * (size_t)N * sizeof(int), stream);
    hipMemsetAsync(denom8, 0, 8 * NSEG * sizeof(float), stream);

    const int QB = (N + MB - 1) / MB;       // 782 row tiles
    const int EB = (E + 1023) / 1024;       // 782 edge chunks
    const int NBSC = (N + SCB - 1) / SCB;   // 25 scan blocks

    w_convert<<<3 * H, 256, 0, stream>>>(Wq, Wk, Wv, wt_hi, wt_lo);

    hist_kernel<<<EB, 256, 0, stream>>>(ei, counts8, N, E);

    qkv_mfma<<<QB, 256, 0, stream>>>(
        x, wt_hi, wt_lo, bq, bk, bv, q, k, v, N);

    scanA<<<NBSC, 256, 0, stream>>>(counts8, counts, offsets, bsum, N);
    scanB<<<1, 64, 0, stream>>>(bsum, NBSC);
    scanC<<<NBSC, 256, 0, stream>>>(bsum, counts8, offsets, cursor8, N);

    reorder_kernel<<<(E + 1023) / 1024, 256, 0, stream>>>(
        ei, batch, cursor8, epack, E, N);

    score_kernel<<<2048, 256, 0, stream>>>(
        q, k, epack, offsets, counts, exps, denom8, N);

    accum_kernel<<<(N + 3) / 4, 256, 0, stream>>>(
        v, exps, epack, offsets, counts, denom8, (float*)d_out, N);
}

// Round 5
// 298.897 us; speedup vs baseline: 1.0906x; 1.0562x over previous
//
#include <hip/hip_runtime.h>

#define H    64
#define F    256
#define NSEG 256
#define SCB  2048   // scan elements per block
#define MB   64     // qkv node rows per tile
#define KC   64     // qkv K chunk
#define XPAD 72     // LDS row stride in shorts (64 + 8: 16B-aligned, 2-way-free)

typedef float          f32x4v __attribute__((ext_vector_type(4)));
typedef short          bf16x8 __attribute__((ext_vector_type(8)));
typedef unsigned short u16x4  __attribute__((ext_vector_type(4)));

// ---------------------------------------------------------------------------
// In-degree histogram, standalone (counts8 1.6 MB stays L2-resident).
// 8-way privatized, copy = blockIdx&7 == (e>>10)&7, matching reorder.
// ---------------------------------------------------------------------------
__global__ __launch_bounds__(256) void hist_kernel(
    const int* __restrict__ ei, int* __restrict__ counts8, int N, int E)
{
    const int pbase = (blockIdx.x & 7) * N;
    const int e0 = blockIdx.x * 1024 + threadIdx.x * 4;
    if (e0 + 3 < E) {
        const int4 d4 = *(const int4*)(ei + E + e0);
        atomicAdd(&counts8[pbase + min(max(d4.x, 0), N - 1)], 1);
        atomicAdd(&counts8[pbase + min(max(d4.y, 0), N - 1)], 1);
        atomicAdd(&counts8[pbase + min(max(d4.z, 0), N - 1)], 1);
        atomicAdd(&counts8[pbase + min(max(d4.w, 0), N - 1)], 1);
    } else {
        for (int e = e0; e < E; ++e) {
            int dst = ei[E + e];
            atomicAdd(&counts8[pbase + min(max(dst, 0), N - 1)], 1);
        }
    }
}

// ---------------------------------------------------------------------------
// QKV GEMM, persistent-W edition.  R3 post-mortem: 782 blocks each re-read
// the whole 196 KB split-W table from L2 (153 MB aggregate) -> bandwidth
// floor far above HBM.  Now: 256 persistent blocks x 12 waves; wave =
// (mat, 16-col tile); its full-K B operand = 64 VGPRs (8x bf16x8 hi + lo),
// split from raw f32 W ONCE per block (w_convert kernel deleted).  Each
// block loops over ~3 row-tiles staging x hi/lo in double-buffered LDS with
// the async-split (issue loads early, convert+ds_write after the MFMAs),
// one barrier per K-chunk.  Numerics identical to previous version:
//   acc += xh*wh + xh*wl + xl*wh    (xl*wl ~ 2^-17 dropped)
// ---------------------------------------------------------------------------
#define CVT_WRITE(buf, rr, cc, val) do {                                      \
    const float ff_[4] = {(val).x, (val).y, (val).z, (val).w};                \
    u16x4 h_, l_;                                                             \
    _Pragma("unroll")                                                         \
    for (int u_ = 0; u_ < 4; ++u_) {                                          \
        unsigned ub_ = __float_as_uint(ff_[u_]);                              \
        h_[u_] = (unsigned short)(ub_ >> 16);                                 \
        float rf_ = ff_[u_] - __uint_as_float(ub_ & 0xFFFF0000u);             \
        l_[u_] = (unsigned short)(__float_as_uint(rf_) >> 16);                \
    }                                                                         \
    *(u16x4*)&xs_hi[buf][(rr) * XPAD + (cc) * 4] = h_;                        \
    *(u16x4*)&xs_lo[buf][(rr) * XPAD + (cc) * 4] = l_;                        \
} while (0)

__global__ __launch_bounds__(768, 3) void qkv_mfma(
    const float* __restrict__ x,
    const float* __restrict__ Wq, const float* __restrict__ Wk,
    const float* __restrict__ Wv,
    const float* __restrict__ bq, const float* __restrict__ bk,
    const float* __restrict__ bv,
    float* __restrict__ q, float* __restrict__ k, float* __restrict__ v,
    int N, int ntiles)
{
    __shared__ unsigned short xs_hi[2][MB * XPAD];   // 2 x 9216 B
    __shared__ unsigned short xs_lo[2][MB * XPAD];   // 2 x 9216 B

    const int t    = threadIdx.x;
    const int lane = t & 63;
    const int w    = t >> 6;        // 0..11
    const int mat  = w >> 2;        // 0..2  (Q,K,V)
    const int ct   = w & 3;         // 16-col tile
    const int l15  = lane & 15;
    const int quad = lane >> 4;

    const float* Wm   = (mat == 0) ? Wq : (mat == 1) ? Wk : Wv;
    const float* bias = (mat == 0) ? bq : (mat == 1) ? bk : bv;
    float*       dst  = (mat == 0) ? q  : (mat == 1) ? k  : v;
    const int col = ct * 16 + l15;
    const float bb = bias[col];

    // ---- W preload: full-K B fragments in registers, split hi/lo in-reg ---
    bf16x8 Bh[8], Bl[8];
    #pragma unroll
    for (int u = 0; u < 8; ++u) {
        #pragma unroll
        for (int j = 0; j < 8; ++j) {
            const float f = Wm[(size_t)(u * 32 + quad * 8 + j) * H + col];
            const unsigned ub = __float_as_uint(f);
            Bh[u][j] = (short)(ub >> 16);
            const float rf = f - __uint_as_float(ub & 0xFFFF0000u);
            Bl[u][j] = (short)(__float_as_uint(rf) >> 16);
        }
    }

    // staging slots: 1024 float4 per chunk; thread t does slot t (always)
    // and slot t+768 (t<256).  (t+768)&15 == t&15 since 768 % 16 == 0.
    const int r0 = t >> 4;
    const int c0 = t & 15;
    const int r1 = (t + 768) >> 4;

    #pragma unroll 1
    for (int tile = blockIdx.x; tile < ntiles; tile += gridDim.x) {
        const int block0 = tile * MB;

        f32x4v acc[4];
        #pragma unroll
        for (int i = 0; i < 4; ++i) acc[i] = (f32x4v)0.f;

        // ---- prologue: chunk 0 into buffer 0 ----
        float4 pv0, pv1;
        pv0 = *(const float4*)(x + (size_t)min(block0 + r0, N - 1) * F + c0 * 4);
        if (t < 256)
            pv1 = *(const float4*)(x + (size_t)min(block0 + r1, N - 1) * F + c0 * 4);
        CVT_WRITE(0, r0, c0, pv0);
        if (t < 256) CVT_WRITE(0, r1, c0, pv1);

        #pragma unroll
        for (int c = 0; c < 4; ++c) {
            __syncthreads();          // buf[c&1] writes visible to all waves

            // issue next chunk's loads EARLY (consumed after the MFMAs)
            if (c < 3) {
                const int kb = (c + 1) * KC;
                pv0 = *(const float4*)(x + (size_t)min(block0 + r0, N - 1) * F + kb + c0 * 4);
                if (t < 256)
                    pv1 = *(const float4*)(x + (size_t)min(block0 + r1, N - 1) * F + kb + c0 * 4);
            }

            // MFMA burst on buf[c&1]; B frags from registers (u = c*2+sk)
            #pragma unroll
            for (int sk = 0; sk < 2; ++sk) {
                const int u = c * 2 + sk;
                #pragma unroll
                for (int mt = 0; mt < 4; ++mt) {
                    const int ao = (mt * 16 + l15) * XPAD + sk * 32 + quad * 8;
                    const bf16x8 ah = *(const bf16x8*)&xs_hi[c & 1][ao];
                    const bf16x8 al = *(const bf16x8*)&xs_lo[c & 1][ao];
                    f32x4v a = acc[mt];
                    a = __builtin_amdgcn_mfma_f32_16x16x32_bf16(ah, Bh[u], a, 0, 0, 0);
                    a = __builtin_amdgcn_mfma_f32_16x16x32_bf16(ah, Bl[u], a, 0, 0, 0);
                    a = __builtin_amdgcn_mfma_f32_16x16x32_bf16(al, Bh[u], a, 0, 0, 0);
                    acc[mt] = a;
                }
            }

            // convert + write next chunk into the other buffer (WAR-safe:
            // buf[nxt] last read in chunk c-1, all waves past top-of-c barrier)
            if (c < 3) {
                const int nb = (c & 1) ^ 1;
                CVT_WRITE(nb, r0, c0, pv0);
                if (t < 256) CVT_WRITE(nb, r1, c0, pv1);
            }
        }

        // epilogue: C layout col = lane&15, row = quad*4 + reg (m89-verified)
        #pragma unroll
        for (int mt = 0; mt < 4; ++mt) {
            #pragma unroll
            for (int r = 0; r < 4; ++r) {
                const int node = block0 + mt * 16 + quad * 4 + r;
                if (node < N)
                    dst[(size_t)node * H + col] = acc[mt][r] + bb;
            }
        }
    }
}

// ---------------------------------------------------------------------------
// Scan phase A/B/C: exclusive scan of padded (x4) per-node total counts.
// scanA sums the 8 private histogram copies and emits the merged counts.
// scanC additionally carves each node's slot range into 8 disjoint per-copy
// sub-ranges (cursor8) so reorder can use privatized returning atomics.
// ---------------------------------------------------------------------------
__global__ __launch_bounds__(256) void scanA(
    const int* __restrict__ counts8, int* __restrict__ counts,
    int* __restrict__ offsets, int* __restrict__ bsum, int n)
{
    __shared__ int ps[256];
    const int t = threadIdx.x;
    const int i0 = blockIdx.x * SCB + t * 8;
    int loc[8];
    int s = 0;
    #pragma unroll
    for (int u = 0; u < 8; ++u) {
        int i = i0 + u;
        int c = 0;
        if (i < n) {
            #pragma unroll
            for (int p = 0; p < 8; ++p) c += counts8[p * n + i];
            counts[i] = c;
            c = (c + 3) & ~3;
        }
        loc[u] = s; s += c;
    }
    ps[t] = s;
    __syncthreads();
    for (int off = 1; off < 256; off <<= 1) {
        int a = (t >= off) ? ps[t - off] : 0;
        __syncthreads();
        ps[t] += a;
        __syncthreads();
    }
    const int base = ps[t] - s;
    #pragma unroll
    for (int u = 0; u < 8; ++u) {
        int i = i0 + u;
        if (i < n) offsets[i] = base + loc[u];
    }
    if (t == 255) bsum[blockIdx.x] = ps[255];
}

__global__ void scanB(int* __restrict__ bsum, int nb)
{
    // single-wave shuffle exclusive scan (nb <= 64)
    const int t = threadIdx.x;
    int v = (t < nb) ? bsum[t] : 0;
    int inc = v;
    #pragma unroll
    for (int off = 1; off < 64; off <<= 1) {
        int u = __shfl_up(inc, off, 64);
        if (t >= off) inc += u;
    }
    if (t < nb) bsum[t] = inc - v;   // exclusive
}

__global__ __launch_bounds__(256) void scanC(
    const int* __restrict__ bsum, const int* __restrict__ counts8,
    int* __restrict__ offsets, int* __restrict__ cursor8, int n)
{
    const int i0 = blockIdx.x * SCB + threadIdx.x * 8;
    const int add = bsum[blockIdx.x];
    #pragma unroll
    for (int u = 0; u < 8; ++u) {
        int i = i0 + u;
        if (i < n) {
            int o = offsets[i] + add;
            offsets[i] = o;
            #pragma unroll
            for (int p = 0; p < 8; ++p) {
                cursor8[p * n + i] = o;       // start of copy p's sub-range
                o += counts8[p * n + i];
            }
        }
    }
}

// ---------------------------------------------------------------------------
// Reorder edges into dst-node order.  pack = src(16b) | seg(8b)<<16.
// Same 1024-edges-per-block shape as the histogram so the edge -> private
// copy mapping (p = (e>>10)&7 = blockIdx&7) matches counts8 exactly.
// ---------------------------------------------------------------------------
__global__ __launch_bounds__(256) void reorder_kernel(
    const int* __restrict__ ei, const int* __restrict__ batch,
    int* __restrict__ cursor8, unsigned* __restrict__ epack, int E, int N)
{
    const int pbase = (blockIdx.x & 7) * N;
    int e = blockIdx.x * 1024 + threadIdx.x;
    #pragma unroll
    for (int u = 0; u < 4; ++u) {
        if (e < E) {
            int src = ei[e];
            int dst = ei[E + e];
            src = min(max(src, 0), N - 1);
            dst = min(max(dst, 0), N - 1);
            int seg = batch[src];
            seg = min(max(seg, 0), NSEG - 1);
            int pos = atomicAdd(&cursor8[pbase + dst], 1);
            epack[pos] = (unsigned)src | ((unsigned)seg << 16);
        }
        e += 256;
    }
}

// ---------------------------------------------------------------------------
// Score: persistent grid, one wave per dst node; q[dst] in registers across
// its edges; 4 edges in flight (16-lane groups, float4 k gathers, 4-step
// shuffle reduce).  Per-block LDS denom histogram flushed once into the
// block's XCD-private denom copy.
// ---------------------------------------------------------------------------
__global__ __launch_bounds__(256) void score_kernel(
    const float* __restrict__ q, const float* __restrict__ k,
    const unsigned* __restrict__ epack,
    const int* __restrict__ offsets, const int* __restrict__ counts,
    float* __restrict__ exps, float* __restrict__ denom8, int N)
{
    __shared__ float sden[NSEG];
    const int t = threadIdx.x;
    sden[t] = 0.f;
    __syncthreads();

    const int lane16 = t & 15;
    const int grp    = (t >> 4) & 3;
    const int wave   = t >> 6;
    const int nwaves = gridDim.x * 4;

    const float4* q4 = (const float4*)q;
    const float4* k4 = (const float4*)k;

    for (int n = blockIdx.x * 4 + wave; n < N; n += nwaves) {
        const int off = offsets[n];
        const int cnt = counts[n];
        if (cnt == 0) continue;
        const float4 qv = q4[(size_t)n * 16 + lane16];
        for (int i = grp; i < cnt; i += 4) {
            const int pos = off + i;
            const unsigned p = epack[pos];
            const int src = p & 0xFFFF;
            const float4 kv = k4[(size_t)src * 16 + lane16];
            float d = kv.x * qv.x + kv.y * qv.y + kv.z * qv.z + kv.w * qv.w;
            d += __shfl_xor(d, 1, 64);
            d += __shfl_xor(d, 2, 64);
            d += __shfl_xor(d, 4, 64);
            d += __shfl_xor(d, 8, 64);
            if (lane16 == 0) {
                float ex = __expf(d * 0.125f);
                exps[pos] = ex;
                atomicAdd(&sden[(p >> 16) & 255], ex);
            }
        }
    }
    __syncthreads();
    float ds = sden[t];
    if (ds != 0.f) atomicAdd(&denom8[(blockIdx.x & 7) * NSEG + t], ds);
}

// ---------------------------------------------------------------------------
// Accumulate: one wave per dst node, lane = feature, register accumulator,
// zero atomics.  LDS reciprocal table built by summing the 8 denom copies.
// ---------------------------------------------------------------------------
__global__ __launch_bounds__(256) void accum_kernel(
    const float* __restrict__ v, const float* __restrict__ exps,
    const unsigned* __restrict__ epack,
    const int* __restrict__ offsets, const int* __restrict__ counts,
    const float* __restrict__ denom8, float* __restrict__ out, int N)
{
    __shared__ float rden[NSEG];
    const int t = threadIdx.x;
    {
        float dsum = 0.f;
        #pragma unroll
        for (int p = 0; p < 8; ++p) dsum += denom8[p * NSEG + t];
        rden[t] = 1.0f / (dsum + 1e-6f);
    }
    __syncthreads();

    const int lane = t & 63;
    const int wave = t >> 6;
    const int n = blockIdx.x * 4 + wave;
    if (n >= N) return;

    const int off = offsets[n];
    const int cnt = counts[n];

    float acc = 0.f;
    int i = 0;
    for (; i + 8 <= cnt; i += 8) {
        const uint4  pa = *(const uint4*)(epack + off + i);
        const uint4  pb = *(const uint4*)(epack + off + i + 4);
        const float4 ea = *(const float4*)(exps + off + i);
        const float4 eb = *(const float4*)(exps + off + i + 4);
        const float v0 = v[(size_t)(pa.x & 0xFFFF) * H + lane];
        const float v1 = v[(size_t)(pa.y & 0xFFFF) * H + lane];
        const float v2 = v[(size_t)(pa.z & 0xFFFF) * H + lane];
        const float v3 = v[(size_t)(pa.w & 0xFFFF) * H + lane];
        const float v4_ = v[(size_t)(pb.x & 0xFFFF) * H + lane];
        const float v5 = v[(size_t)(pb.y & 0xFFFF) * H + lane];
        const float v6 = v[(size_t)(pb.z & 0xFFFF) * H + lane];
        const float v7 = v[(size_t)(pb.w & 0xFFFF) * H + lane];
        acc = fmaf(v0, ea.x * rden[(pa.x >> 16) & 255], acc);
        acc = fmaf(v1, ea.y * rden[(pa.y >> 16) & 255], acc);
        acc = fmaf(v2, ea.z * rden[(pa.z >> 16) & 255], acc);
        acc = fmaf(v3, ea.w * rden[(pa.w >> 16) & 255], acc);
        acc = fmaf(v4_, eb.x * rden[(pb.x >> 16) & 255], acc);
        acc = fmaf(v5, eb.y * rden[(pb.y >> 16) & 255], acc);
        acc = fmaf(v6, eb.z * rden[(pb.z >> 16) & 255], acc);
        acc = fmaf(v7, eb.w * rden[(pb.w >> 16) & 255], acc);
    }
    for (; i + 4 <= cnt; i += 4) {
        const uint4  pp = *(const uint4*)(epack + off + i);
        const float4 ee = *(const float4*)(exps + off + i);
        const float v0 = v[(size_t)(pp.x & 0xFFFF) * H + lane];
        const float v1 = v[(size_t)(pp.y & 0xFFFF) * H + lane];
        const float v2 = v[(size_t)(pp.z & 0xFFFF) * H + lane];
        const float v3 = v[(size_t)(pp.w & 0xFFFF) * H + lane];
        acc = fmaf(v0, ee.x * rden[(pp.x >> 16) & 255], acc);
        acc = fmaf(v1, ee.y * rden[(pp.y >> 16) & 255], acc);
        acc = fmaf(v2, ee.z * rden[(pp.z >> 16) & 255], acc);
        acc = fmaf(v3, ee.w * rden[(pp.w >> 16) & 255], acc);
    }
    for (; i < cnt; ++i) {
        const unsigned p = epack[off + i];
        acc = fmaf(v[(size_t)(p & 0xFFFF) * H + lane],
                   exps[off + i] * rden[(p >> 16) & 255], acc);
    }
    out[(size_t)n * H + lane] = acc;
}

extern "C" void kernel_launch(void* const* d_in, const int* in_sizes, int n_in,
                              void* d_out, int out_size, void* d_ws, size_t ws_size,
                              hipStream_t stream)
{
    const float* x   = (const float*)d_in[0];
    const float* Wq  = (const float*)d_in[1];
    const float* bq  = (const float*)d_in[2];
    const float* Wk  = (const float*)d_in[3];
    const float* bk  = (const float*)d_in[4];
    const float* Wv  = (const float*)d_in[5];
    const float* bv  = (const float*)d_in[6];
    const int* ei    = (const int*)d_in[7];
    const int* batch = (const int*)d_in[8];

    const int N = in_sizes[8];        // 50000
    const int E = in_sizes[7] / 2;    // 800000
    const int EP = E + 3 * N + 16;    // padded edge-slot capacity

    float*    q       = (float*)d_ws;
    float*    k       = q + (size_t)N * H;
    float*    v       = k + (size_t)N * H;
    float*    exps    = v + (size_t)N * H;
    unsigned* epack   = (unsigned*)(exps + EP);
    int*      counts  = (int*)(epack + EP);
    int*      offsets = counts + N;
    int*      bsum    = offsets + N;
    float*    denom8  = (float*)(bsum + 64);

    // Aliased scratch (lifetimes verified disjoint):
    //   counts8 (8N ints) lives in epack's slots: last read in scanC,
    //     epack first written in reorder.
    //   cursor8 (8N ints) lives in exps' slots: last touched in reorder,
    //     exps first written in score.
    int* counts8 = (int*)epack;
    int* cursor8 = (int*)exps;

    hipMemsetAsync(counts8, 0, 8 * (size_t)N * sizeof(int), stream);
    hipMemsetAsync(denom8, 0, 8 * NSEG * sizeof(float), stream);

    const int NT = (N + MB - 1) / MB;       // 782 row tiles
    const int EB = (E + 1023) / 1024;       // 782 edge chunks
    const int NBSC = (N + SCB - 1) / SCB;   // 25 scan blocks

    hist_kernel<<<EB, 256, 0, stream>>>(ei, counts8, N, E);

    qkv_mfma<<<256, 768, 0, stream>>>(
        x, Wq, Wk, Wv, bq, bk, bv, q, k, v, N, NT);

    scanA<<<NBSC, 256, 0, stream>>>(counts8, counts, offsets, bsum, N);
    scanB<<<1, 64, 0, stream>>>(bsum, NBSC);
    scanC<<<NBSC, 256, 0, stream>>>(bsum, counts8, offsets, cursor8, N);

    reorder_kernel<<<(E + 1023) / 1024, 256, 0, stream>>>(
        ei, batch, cursor8, epack, E, N);

    score_kernel<<<2048, 256, 0, stream>>>(
        q, k, epack, offsets, counts, exps, denom8, N);

    accum_kernel<<<(N + 3) / 4, 256, 0, stream>>>(
        v, exps, epack, offsets, counts, denom8, (float*)d_out, N);
}

// Round 6
// 285.354 us; speedup vs baseline: 1.1423x; 1.0475x over previous
//
#include <hip/hip_runtime.h>

#define H    64
#define F    256
#define NSEG 256
#define SCB  2048   // scan elements per block
#define MB   64     // qkv node rows per tile
#define KC   64     // qkv K chunk
#define XPAD 72     // LDS row stride in shorts (64 + 8: 16B-aligned, 2-way-free)

typedef float          f32x4v __attribute__((ext_vector_type(4)));
typedef short          bf16x8 __attribute__((ext_vector_type(8)));
typedef unsigned short u16x4  __attribute__((ext_vector_type(4)));

// ---------------------------------------------------------------------------
// In-degree histogram, dst-range partitioned.  R5 post-mortem: edge-chunk
// privatization left each node's count/epack lines shared by all 8 XCDs ->
// one HBM line write-back per edge (WRITE_SIZE 49.5 MB for 3.2 MB payload).
// Now: span p = nodes [p*nspan, (p+1)*nspan) is touched ONLY by blocks with
// blockIdx&7 == p (XCD-local lines, written back once).  Cost: 8x re-read
// of the dst array (L3-hot, cheap).  Single counts array, no 8-copy.
// ---------------------------------------------------------------------------
__global__ __launch_bounds__(256) void hist_kernel(
    const int* __restrict__ ei, int* __restrict__ counts,
    int N, int E, int nspan)
{
    const int p  = blockIdx.x & 7;
    const int ci = blockIdx.x >> 3;
    const int lo = p * nspan;
    const int hi = min(N, lo + nspan);
    const int e0 = ci * 1024 + threadIdx.x * 4;
    if (e0 + 3 < E) {
        const int4 d4 = *(const int4*)(ei + E + e0);
        int d;
        d = min(max(d4.x, 0), N - 1); if (d >= lo && d < hi) atomicAdd(&counts[d], 1);
        d = min(max(d4.y, 0), N - 1); if (d >= lo && d < hi) atomicAdd(&counts[d], 1);
        d = min(max(d4.z, 0), N - 1); if (d >= lo && d < hi) atomicAdd(&counts[d], 1);
        d = min(max(d4.w, 0), N - 1); if (d >= lo && d < hi) atomicAdd(&counts[d], 1);
    } else {
        for (int e = e0; e < E; ++e) {
            int d = min(max(ei[E + e], 0), N - 1);
            if (d >= lo && d < hi) atomicAdd(&counts[d], 1);
        }
    }
}

// ---------------------------------------------------------------------------
// QKV GEMM, persistent-W edition (R5-verified: out of the top-5).
// 256 persistent blocks x 12 waves; wave = (mat, 16-col tile); full-K B
// operand in 64 VGPRs, split from raw f32 W once per block.  Per row-tile:
// double-buffered LDS staging of x hi/lo with async-split, 1 barrier/chunk.
//   acc += xh*wh + xh*wl + xl*wh    (xl*wl ~ 2^-17 dropped)
// ---------------------------------------------------------------------------
#define CVT_WRITE(buf, rr, cc, val) do {                                      \
    const float ff_[4] = {(val).x, (val).y, (val).z, (val).w};                \
    u16x4 h_, l_;                                                             \
    _Pragma("unroll")                                                         \
    for (int u_ = 0; u_ < 4; ++u_) {                                          \
        unsigned ub_ = __float_as_uint(ff_[u_]);                              \
        h_[u_] = (unsigned short)(ub_ >> 16);                                 \
        float rf_ = ff_[u_] - __uint_as_float(ub_ & 0xFFFF0000u);             \
        l_[u_] = (unsigned short)(__float_as_uint(rf_) >> 16);                \
    }                                                                         \
    *(u16x4*)&xs_hi[buf][(rr) * XPAD + (cc) * 4] = h_;                        \
    *(u16x4*)&xs_lo[buf][(rr) * XPAD + (cc) * 4] = l_;                        \
} while (0)

__global__ __launch_bounds__(768, 3) void qkv_mfma(
    const float* __restrict__ x,
    const float* __restrict__ Wq, const float* __restrict__ Wk,
    const float* __restrict__ Wv,
    const float* __restrict__ bq, const float* __restrict__ bk,
    const float* __restrict__ bv,
    float* __restrict__ q, float* __restrict__ k, float* __restrict__ v,
    int N, int ntiles)
{
    __shared__ unsigned short xs_hi[2][MB * XPAD];   // 2 x 9216 B
    __shared__ unsigned short xs_lo[2][MB * XPAD];   // 2 x 9216 B

    const int t    = threadIdx.x;
    const int lane = t & 63;
    const int w    = t >> 6;        // 0..11
    const int mat  = w >> 2;        // 0..2  (Q,K,V)
    const int ct   = w & 3;         // 16-col tile
    const int l15  = lane & 15;
    const int quad = lane >> 4;

    const float* Wm   = (mat == 0) ? Wq : (mat == 1) ? Wk : Wv;
    const float* bias = (mat == 0) ? bq : (mat == 1) ? bk : bv;
    float*       dst  = (mat == 0) ? q  : (mat == 1) ? k  : v;
    const int col = ct * 16 + l15;
    const float bb = bias[col];

    // ---- W preload: full-K B fragments in registers, split hi/lo in-reg ---
    bf16x8 Bh[8], Bl[8];
    #pragma unroll
    for (int u = 0; u < 8; ++u) {
        #pragma unroll
        for (int j = 0; j < 8; ++j) {
            const float f = Wm[(size_t)(u * 32 + quad * 8 + j) * H + col];
            const unsigned ub = __float_as_uint(f);
            Bh[u][j] = (short)(ub >> 16);
            const float rf = f - __uint_as_float(ub & 0xFFFF0000u);
            Bl[u][j] = (short)(__float_as_uint(rf) >> 16);
        }
    }

    // staging slots: 1024 float4 per chunk; thread t does slot t (always)
    // and slot t+768 (t<256).  (t+768)&15 == t&15 since 768 % 16 == 0.
    const int r0 = t >> 4;
    const int c0 = t & 15;
    const int r1 = (t + 768) >> 4;

    #pragma unroll 1
    for (int tile = blockIdx.x; tile < ntiles; tile += gridDim.x) {
        const int block0 = tile * MB;

        f32x4v acc[4];
        #pragma unroll
        for (int i = 0; i < 4; ++i) acc[i] = (f32x4v)0.f;

        // ---- prologue: chunk 0 into buffer 0 ----
        float4 pv0, pv1;
        pv0 = *(const float4*)(x + (size_t)min(block0 + r0, N - 1) * F + c0 * 4);
        if (t < 256)
            pv1 = *(const float4*)(x + (size_t)min(block0 + r1, N - 1) * F + c0 * 4);
        CVT_WRITE(0, r0, c0, pv0);
        if (t < 256) CVT_WRITE(0, r1, c0, pv1);

        #pragma unroll
        for (int c = 0; c < 4; ++c) {
            __syncthreads();          // buf[c&1] writes visible to all waves

            // issue next chunk's loads EARLY (consumed after the MFMAs)
            if (c < 3) {
                const int kb = (c + 1) * KC;
                pv0 = *(const float4*)(x + (size_t)min(block0 + r0, N - 1) * F + kb + c0 * 4);
                if (t < 256)
                    pv1 = *(const float4*)(x + (size_t)min(block0 + r1, N - 1) * F + kb + c0 * 4);
            }

            // MFMA burst on buf[c&1]; B frags from registers (u = c*2+sk)
            #pragma unroll
            for (int sk = 0; sk < 2; ++sk) {
                const int u = c * 2 + sk;
                #pragma unroll
                for (int mt = 0; mt < 4; ++mt) {
                    const int ao = (mt * 16 + l15) * XPAD + sk * 32 + quad * 8;
                    const bf16x8 ah = *(const bf16x8*)&xs_hi[c & 1][ao];
                    const bf16x8 al = *(const bf16x8*)&xs_lo[c & 1][ao];
                    f32x4v a = acc[mt];
                    a = __builtin_amdgcn_mfma_f32_16x16x32_bf16(ah, Bh[u], a, 0, 0, 0);
                    a = __builtin_amdgcn_mfma_f32_16x16x32_bf16(ah, Bl[u], a, 0, 0, 0);
                    a = __builtin_amdgcn_mfma_f32_16x16x32_bf16(al, Bh[u], a, 0, 0, 0);
                    acc[mt] = a;
                }
            }

            // convert + write next chunk into the other buffer (WAR-safe:
            // buf[nxt] last read in chunk c-1, all waves past top-of-c barrier)
            if (c < 3) {
                const int nb = (c & 1) ^ 1;
                CVT_WRITE(nb, r0, c0, pv0);
                if (t < 256) CVT_WRITE(nb, r1, c0, pv1);
            }
        }

        // epilogue: C layout col = lane&15, row = quad*4 + reg (m89-verified)
        #pragma unroll
        for (int mt = 0; mt < 4; ++mt) {
            #pragma unroll
            for (int r = 0; r < 4; ++r) {
                const int node = block0 + mt * 16 + quad * 4 + r;
                if (node < N)
                    dst[(size_t)node * H + col] = acc[mt][r] + bb;
            }
        }
    }
}

// ---------------------------------------------------------------------------
// Scan phase A/B/C: exclusive scan of padded (x4) per-node counts.
// (Single counts array now; no 8-copy merge or sub-range carving.)
// ---------------------------------------------------------------------------
__global__ __launch_bounds__(256) void scanA(
    const int* __restrict__ counts, int* __restrict__ offsets,
    int* __restrict__ bsum, int n)
{
    __shared__ int ps[256];
    const int t = threadIdx.x;
    const int i0 = blockIdx.x * SCB + t * 8;
    int loc[8];
    int s = 0;
    #pragma unroll
    for (int u = 0; u < 8; ++u) {
        int i = i0 + u;
        int c = (i < n) ? ((counts[i] + 3) & ~3) : 0;
        loc[u] = s; s += c;
    }
    ps[t] = s;
    __syncthreads();
    for (int off = 1; off < 256; off <<= 1) {
        int a = (t >= off) ? ps[t - off] : 0;
        __syncthreads();
        ps[t] += a;
        __syncthreads();
    }
    const int base = ps[t] - s;
    #pragma unroll
    for (int u = 0; u < 8; ++u) {
        int i = i0 + u;
        if (i < n) offsets[i] = base + loc[u];
    }
    if (t == 255) bsum[blockIdx.x] = ps[255];
}

__global__ void scanB(int* __restrict__ bsum, int nb)
{
    // single-wave shuffle exclusive scan (nb <= 64)
    const int t = threadIdx.x;
    int v = (t < nb) ? bsum[t] : 0;
    int inc = v;
    #pragma unroll
    for (int off = 1; off < 64; off <<= 1) {
        int u = __shfl_up(inc, off, 64);
        if (t >= off) inc += u;
    }
    if (t < nb) bsum[t] = inc - v;   // exclusive
}

__global__ __launch_bounds__(256) void scanC(
    const int* __restrict__ bsum, int* __restrict__ offsets,
    int* __restrict__ cursor, int n)
{
    const int i0 = blockIdx.x * SCB + threadIdx.x * 8;
    const int add = bsum[blockIdx.x];
    #pragma unroll
    for (int u = 0; u < 8; ++u) {
        int i = i0 + u;
        if (i < n) { int o = offsets[i] + add; offsets[i] = o; cursor[i] = o; }
    }
}

// ---------------------------------------------------------------------------
// Reorder edges into dst-node order, dst-range partitioned (see hist).
// Blocks of class p = blockIdx&7 write ONLY dst-span p: epack/cursor lines
// are single-XCD -> stay L2-resident, written back once (was: one HBM line
// write-back per edge).  pack = src(16b) | seg(8b)<<16.
// ---------------------------------------------------------------------------
__global__ __launch_bounds__(256) void reorder_kernel(
    const int* __restrict__ ei, const int* __restrict__ batch,
    int* __restrict__ cursor, unsigned* __restrict__ epack,
    int E, int N, int nspan)
{
    const int p  = blockIdx.x & 7;
    const int ci = blockIdx.x >> 3;
    const int lo = p * nspan;
    const int hi = min(N, lo + nspan);
    const int e0 = ci * 1024 + threadIdx.x * 4;

    int d[4];
    if (e0 + 3 < E) {
        const int4 d4 = *(const int4*)(ei + E + e0);
        d[0] = d4.x; d[1] = d4.y; d[2] = d4.z; d[3] = d4.w;
    } else {
        #pragma unroll
        for (int u = 0; u < 4; ++u)
            d[u] = (e0 + u < E) ? ei[E + e0 + u] : -1;   // -1: never in span
    }

    #pragma unroll
    for (int u = 0; u < 4; ++u) {
        const int dst = min(max(d[u], 0), N - 1);
        if (d[u] >= 0 && dst >= lo && dst < hi) {
            int src = ei[e0 + u];
            src = min(max(src, 0), N - 1);
            int seg = batch[src];
            seg = min(max(seg, 0), NSEG - 1);
            const int pos = atomicAdd(&cursor[dst], 1);
            epack[pos] = (unsigned)src | ((unsigned)seg << 16);
        }
    }
}

// ---------------------------------------------------------------------------
// Score: persistent grid, one wave per dst node; q[dst] in registers across
// its edges; 4 edges in flight (16-lane groups, float4 k gathers, 4-step
// shuffle reduce).  Per-block LDS denom histogram flushed once into the
// block's XCD-private denom copy.
// ---------------------------------------------------------------------------
__global__ __launch_bounds__(256) void score_kernel(
    const float* __restrict__ q, const float* __restrict__ k,
    const unsigned* __restrict__ epack,
    const int* __restrict__ offsets, const int* __restrict__ counts,
    float* __restrict__ exps, float* __restrict__ denom8, int N)
{
    __shared__ float sden[NSEG];
    const int t = threadIdx.x;
    sden[t] = 0.f;
    __syncthreads();

    const int lane16 = t & 15;
    const int grp    = (t >> 4) & 3;
    const int wave   = t >> 6;
    const int nwaves = gridDim.x * 4;

    const float4* q4 = (const float4*)q;
    const float4* k4 = (const float4*)k;

    for (int n = blockIdx.x * 4 + wave; n < N; n += nwaves) {
        const int off = offsets[n];
        const int cnt = counts[n];
        if (cnt == 0) continue;
        const float4 qv = q4[(size_t)n * 16 + lane16];
        for (int i = grp; i < cnt; i += 4) {
            const int pos = off + i;
            const unsigned p = epack[pos];
            const int src = p & 0xFFFF;
            const float4 kv = k4[(size_t)src * 16 + lane16];
            float d = kv.x * qv.x + kv.y * qv.y + kv.z * qv.z + kv.w * qv.w;
            d += __shfl_xor(d, 1, 64);
            d += __shfl_xor(d, 2, 64);
            d += __shfl_xor(d, 4, 64);
            d += __shfl_xor(d, 8, 64);
            if (lane16 == 0) {
                float ex = __expf(d * 0.125f);
                exps[pos] = ex;
                atomicAdd(&sden[(p >> 16) & 255], ex);
            }
        }
    }
    __syncthreads();
    float ds = sden[t];
    if (ds != 0.f) atomicAdd(&denom8[(blockIdx.x & 7) * NSEG + t], ds);
}

// ---------------------------------------------------------------------------
// Accumulate: one wave per dst node, lane = feature, register accumulator,
// zero atomics.  LDS reciprocal table built by summing the 8 denom copies.
// ---------------------------------------------------------------------------
__global__ __launch_bounds__(256) void accum_kernel(
    const float* __restrict__ v, const float* __restrict__ exps,
    const unsigned* __restrict__ epack,
    const int* __restrict__ offsets, const int* __restrict__ counts,
    const float* __restrict__ denom8, float* __restrict__ out, int N)
{
    __shared__ float rden[NSEG];
    const int t = threadIdx.x;
    {
        float dsum = 0.f;
        #pragma unroll
        for (int p = 0; p < 8; ++p) dsum += denom8[p * NSEG + t];
        rden[t] = 1.0f / (dsum + 1e-6f);
    }
    __syncthreads();

    const int lane = t & 63;
    const int wave = t >> 6;
    const int n = blockIdx.x * 4 + wave;
    if (n >= N) return;

    const int off = offsets[n];
    const int cnt = counts[n];

    float acc = 0.f;
    int i = 0;
    for (; i + 8 <= cnt; i += 8) {
        const uint4  pa = *(const uint4*)(epack + off + i);
        const uint4  pb = *(const uint4*)(epack + off + i + 4);
        const float4 ea = *(const float4*)(exps + off + i);
        const float4 eb = *(const float4*)(exps + off + i + 4);
        const float v0 = v[(size_t)(pa.x & 0xFFFF) * H + lane];
        const float v1 = v[(size_t)(pa.y & 0xFFFF) * H + lane];
        const float v2 = v[(size_t)(pa.z & 0xFFFF) * H + lane];
        const float v3 = v[(size_t)(pa.w & 0xFFFF) * H + lane];
        const float v4_ = v[(size_t)(pb.x & 0xFFFF) * H + lane];
        const float v5 = v[(size_t)(pb.y & 0xFFFF) * H + lane];
        const float v6 = v[(size_t)(pb.z & 0xFFFF) * H + lane];
        const float v7 = v[(size_t)(pb.w & 0xFFFF) * H + lane];
        acc = fmaf(v0, ea.x * rden[(pa.x >> 16) & 255], acc);
        acc = fmaf(v1, ea.y * rden[(pa.y >> 16) & 255], acc);
        acc = fmaf(v2, ea.z * rden[(pa.z >> 16) & 255], acc);
        acc = fmaf(v3, ea.w * rden[(pa.w >> 16) & 255], acc);
        acc = fmaf(v4_, eb.x * rden[(pb.x >> 16) & 255], acc);
        acc = fmaf(v5, eb.y * rden[(pb.y >> 16) & 255], acc);
        acc = fmaf(v6, eb.z * rden[(pb.z >> 16) & 255], acc);
        acc = fmaf(v7, eb.w * rden[(pb.w >> 16) & 255], acc);
    }
    for (; i + 4 <= cnt; i += 4) {
        const uint4  pp = *(const uint4*)(epack + off + i);
        const float4 ee = *(const float4*)(exps + off + i);
        const float v0 = v[(size_t)(pp.x & 0xFFFF) * H + lane];
        const float v1 = v[(size_t)(pp.y & 0xFFFF) * H + lane];
        const float v2 = v[(size_t)(pp.z & 0xFFFF) * H + lane];
        const float v3 = v[(size_t)(pp.w & 0xFFFF) * H + lane];
        acc = fmaf(v0, ee.x * rden[(pp.x >> 16) & 255], acc);
        acc = fmaf(v1, ee.y * rden[(pp.y >> 16) & 255], acc);
        acc = fmaf(v2, ee.z * rden[(pp.z >> 16) & 255], acc);
        acc = fmaf(v3, ee.w * rden[(pp.w >> 16) & 255], acc);
    }
    for (; i < cnt; ++i) {
        const unsigned p = epack[off + i];
        acc = fmaf(v[(size_t)(p & 0xFFFF) * H + lane],
                   exps[off + i] * rden[(p >> 16) & 255], acc);
    }
    out[(size_t)n * H + lane] = acc;
}

extern "C" void kernel_launch(void* const* d_in, const int* in_sizes, int n_in,
                              void* d_out, int out_size, void* d_ws, size_t ws_size,
                              hipStream_t stream)
{
    const float* x   = (const float*)d_in[0];
    const float* Wq  = (const float*)d_in[1];
    const float* bq  = (const float*)d_in[2];
    const float* Wk  = (const float*)d_in[3];
    const float* bk  = (const float*)d_in[4];
    const float* Wv  = (const float*)d_in[5];
    const float* bv  = (const float*)d_in[6];
    const int* ei    = (const int*)d_in[7];
    const int* batch = (const int*)d_in[8];

    const int N = in_sizes[8];        // 50000
    const int E = in_sizes[7] / 2;    // 800000
    const int EP = E + 3 * N + 16;    // padded edge-slot capacity

    float*    q       = (float*)d_ws;
    float*    k       = q + (size_t)N * H;
    float*    v       = k + (size_t)N * H;
    float*    exps    = v + (size_t)N * H;
    unsigned* epack   = (unsigned*)(exps + EP);
    int*      counts  = (int*)(epack + EP);
    int*      offsets = counts + N;
    int*      cursor  = offsets + N;
    int*      bsum    = cursor + N;
    float*    denom8  = (float*)(bsum + 64);

    hipMemsetAsync(counts, 0, N * sizeof(int), stream);
    hipMemsetAsync(denom8, 0, 8 * NSEG * sizeof(float), stream);

    const int NT    = (N + MB - 1) / MB;     // 782 row tiles
    const int NC    = (E + 1023) / 1024;     // 782 edge chunks
    const int nspan = (N + 7) / 8;           // dst-range span per XCD class
    const int NBSC  = (N + SCB - 1) / SCB;   // 25 scan blocks

    hist_kernel<<<8 * NC, 256, 0, stream>>>(ei, counts, N, E, nspan);

    qkv_mfma<<<256, 768, 0, stream>>>(
        x, Wq, Wk, Wv, bq, bk, bv, q, k, v, N, NT);

    scanA<<<NBSC, 256, 0, stream>>>(counts, offsets, bsum, N);
    scanB<<<1, 64, 0, stream>>>(bsum, NBSC);
    scanC<<<NBSC, 256, 0, stream>>>(bsum, offsets, cursor, N);

    reorder_kernel<<<8 * NC, 256, 0, stream>>>(
        ei, batch, cursor, epack, E, N, nspan);

    score_kernel<<<2048, 256, 0, stream>>>(
        q, k, epack, offsets, counts, exps, denom8, N);

    accum_kernel<<<(N + 3) / 4, 256, 0, stream>>>(
        v, exps, epack, offsets, counts, denom8, (float*)d_out, N);
}

// Round 7
// 283.040 us; speedup vs baseline: 1.1517x; 1.0082x over previous
//
#include <hip/hip_runtime.h>

#define H    64
#define F    256
#define NSEG 256
#define SCB  2048   // scan elements per block
#define MB   64     // qkv node rows per tile
#define KC   64     // qkv K chunk
#define XPAD 72     // LDS row stride in shorts (64 + 8: 16B-aligned, odd 16B-stride)

typedef float          f32x4v __attribute__((ext_vector_type(4)));
typedef short          bf16x8 __attribute__((ext_vector_type(8)));
typedef unsigned short u16x4  __attribute__((ext_vector_type(4)));

// ---------------------------------------------------------------------------
// In-degree histogram, dst-range partitioned (R6-verified).  Span p = nodes
// [p*nspan,(p+1)*nspan) touched only by blocks with blockIdx&7==p ->
// count lines are XCD-local.  Cost: 8x re-read of dst array (L3-hot).
// ---------------------------------------------------------------------------
__global__ __launch_bounds__(256) void hist_kernel(
    const int* __restrict__ ei, int* __restrict__ counts,
    int N, int E, int nspan)
{
    const int p  = blockIdx.x & 7;
    const int ci = blockIdx.x >> 3;
    const int lo = p * nspan;
    const int hi = min(N, lo + nspan);
    const int e0 = ci * 1024 + threadIdx.x * 4;
    if (e0 + 3 < E) {
        const int4 d4 = *(const int4*)(ei + E + e0);
        int d;
        d = min(max(d4.x, 0), N - 1); if (d >= lo && d < hi) atomicAdd(&counts[d], 1);
        d = min(max(d4.y, 0), N - 1); if (d >= lo && d < hi) atomicAdd(&counts[d], 1);
        d = min(max(d4.z, 0), N - 1); if (d >= lo && d < hi) atomicAdd(&counts[d], 1);
        d = min(max(d4.w, 0), N - 1); if (d >= lo && d < hi) atomicAdd(&counts[d], 1);
    } else {
        for (int e = e0; e < E; ++e) {
            int d = min(max(ei[E + e], 0), N - 1);
            if (d >= lo && d < hi) atomicAdd(&counts[d], 1);
        }
    }
}

// ---------------------------------------------------------------------------
// QKV GEMM, persistent-W.  R6 post-mortem: at 1 block/CU (grid 256) every
// barrier is a dead stop (no co-resident block to fill the bubble) and the
// 782-tile tail stretches 14 CUs to a 4th tile.  VGPR=60 (<=64) allows
// 8 waves/SIMD and LDS is 36.9 KB -> TWO 768-thread blocks fit per CU.
// Grid 512 = 2 blocks/CU: partner block fills barrier bubbles, tail overlaps.
// Kernel body unchanged from R6 (single-variable change).
//   acc += xh*wh + xh*wl + xl*wh    (xl*wl ~ 2^-17 dropped)
// ---------------------------------------------------------------------------
#define CVT_WRITE(buf, rr, cc, val) do {                                      \
    const float ff_[4] = {(val).x, (val).y, (val).z, (val).w};                \
    u16x4 h_, l_;                                                             \
    _Pragma("unroll")                                                         \
    for (int u_ = 0; u_ < 4; ++u_) {                                          \
        unsigned ub_ = __float_as_uint(ff_[u_]);                              \
        h_[u_] = (unsigned short)(ub_ >> 16);                                 \
        float rf_ = ff_[u_] - __uint_as_float(ub_ & 0xFFFF0000u);             \
        l_[u_] = (unsigned short)(__float_as_uint(rf_) >> 16);                \
    }                                                                         \
    *(u16x4*)&xs_hi[buf][(rr) * XPAD + (cc) * 4] = h_;                        \
    *(u16x4*)&xs_lo[buf][(rr) * XPAD + (cc) * 4] = l_;                        \
} while (0)

__global__ __launch_bounds__(768, 3) void qkv_mfma(
    const float* __restrict__ x,
    const float* __restrict__ Wq, const float* __restrict__ Wk,
    const float* __restrict__ Wv,
    const float* __restrict__ bq, const float* __restrict__ bk,
    const float* __restrict__ bv,
    float* __restrict__ q, float* __restrict__ k, float* __restrict__ v,
    int N, int ntiles)
{
    __shared__ unsigned short xs_hi[2][MB * XPAD];   // 2 x 9216 B
    __shared__ unsigned short xs_lo[2][MB * XPAD];   // 2 x 9216 B

    const int t    = threadIdx.x;
    const int lane = t & 63;
    const int w    = t >> 6;        // 0..11
    const int mat  = w >> 2;        // 0..2  (Q,K,V)
    const int ct   = w & 3;         // 16-col tile
    const int l15  = lane & 15;
    const int quad = lane >> 4;

    const float* Wm   = (mat == 0) ? Wq : (mat == 1) ? Wk : Wv;
    const float* bias = (mat == 0) ? bq : (mat == 1) ? bk : bv;
    float*       dst  = (mat == 0) ? q  : (mat == 1) ? k  : v;
    const int col = ct * 16 + l15;
    const float bb = bias[col];

    // ---- W preload: full-K B fragments in registers, split hi/lo in-reg ---
    bf16x8 Bh[8], Bl[8];
    #pragma unroll
    for (int u = 0; u < 8; ++u) {
        #pragma unroll
        for (int j = 0; j < 8; ++j) {
            const float f = Wm[(size_t)(u * 32 + quad * 8 + j) * H + col];
            const unsigned ub = __float_as_uint(f);
            Bh[u][j] = (short)(ub >> 16);
            const float rf = f - __uint_as_float(ub & 0xFFFF0000u);
            Bl[u][j] = (short)(__float_as_uint(rf) >> 16);
        }
    }

    // staging slots: 1024 float4 per chunk; thread t does slot t (always)
    // and slot t+768 (t<256).  (t+768)&15 == t&15 since 768 % 16 == 0.
    const int r0 = t >> 4;
    const int c0 = t & 15;
    const int r1 = (t + 768) >> 4;

    #pragma unroll 1
    for (int tile = blockIdx.x; tile < ntiles; tile += gridDim.x) {
        const int block0 = tile * MB;

        f32x4v acc[4];
        #pragma unroll
        for (int i = 0; i < 4; ++i) acc[i] = (f32x4v)0.f;

        // ---- prologue: chunk 0 into buffer 0 ----
        float4 pv0, pv1;
        pv0 = *(const float4*)(x + (size_t)min(block0 + r0, N - 1) * F + c0 * 4);
        if (t < 256)
            pv1 = *(const float4*)(x + (size_t)min(block0 + r1, N - 1) * F + c0 * 4);
        CVT_WRITE(0, r0, c0, pv0);
        if (t < 256) CVT_WRITE(0, r1, c0, pv1);

        #pragma unroll
        for (int c = 0; c < 4; ++c) {
            __syncthreads();          // buf[c&1] writes visible to all waves

            // issue next chunk's loads EARLY (consumed after the MFMAs)
            if (c < 3) {
                const int kb = (c + 1) * KC;
                pv0 = *(const float4*)(x + (size_t)min(block0 + r0, N - 1) * F + kb + c0 * 4);
                if (t < 256)
                    pv1 = *(const float4*)(x + (size_t)min(block0 + r1, N - 1) * F + kb + c0 * 4);
            }

            // MFMA burst on buf[c&1]; B frags from registers (u = c*2+sk)
            #pragma unroll
            for (int sk = 0; sk < 2; ++sk) {
                const int u = c * 2 + sk;
                #pragma unroll
                for (int mt = 0; mt < 4; ++mt) {
                    const int ao = (mt * 16 + l15) * XPAD + sk * 32 + quad * 8;
                    const bf16x8 ah = *(const bf16x8*)&xs_hi[c & 1][ao];
                    const bf16x8 al = *(const bf16x8*)&xs_lo[c & 1][ao];
                    f32x4v a = acc[mt];
                    a = __builtin_amdgcn_mfma_f32_16x16x32_bf16(ah, Bh[u], a, 0, 0, 0);
                    a = __builtin_amdgcn_mfma_f32_16x16x32_bf16(ah, Bl[u], a, 0, 0, 0);
                    a = __builtin_amdgcn_mfma_f32_16x16x32_bf16(al, Bh[u], a, 0, 0, 0);
                    acc[mt] = a;
                }
            }

            // convert + write next chunk into the other buffer (WAR-safe:
            // buf[nxt] last read in chunk c-1, all waves past top-of-c barrier)
            if (c < 3) {
                const int nb = (c & 1) ^ 1;
                CVT_WRITE(nb, r0, c0, pv0);
                if (t < 256) CVT_WRITE(nb, r1, c0, pv1);
            }
        }

        // epilogue: C layout col = lane&15, row = quad*4 + reg (m89-verified)
        #pragma unroll
        for (int mt = 0; mt < 4; ++mt) {
            #pragma unroll
            for (int r = 0; r < 4; ++r) {
                const int node = block0 + mt * 16 + quad * 4 + r;
                if (node < N)
                    dst[(size_t)node * H + col] = acc[mt][r] + bb;
            }
        }
    }
}

// ---------------------------------------------------------------------------
// Scan phase A/B/C: exclusive scan of padded (x4) per-node counts.
// ---------------------------------------------------------------------------
__global__ __launch_bounds__(256) void scanA(
    const int* __restrict__ counts, int* __restrict__ offsets,
    int* __restrict__ bsum, int n)
{
    __shared__ int ps[256];
    const int t = threadIdx.x;
    const int i0 = blockIdx.x * SCB + t * 8;
    int loc[8];
    int s = 0;
    #pragma unroll
    for (int u = 0; u < 8; ++u) {
        int i = i0 + u;
        int c = (i < n) ? ((counts[i] + 3) & ~3) : 0;
        loc[u] = s; s += c;
    }
    ps[t] = s;
    __syncthreads();
    for (int off = 1; off < 256; off <<= 1) {
        int a = (t >= off) ? ps[t - off] : 0;
        __syncthreads();
        ps[t] += a;
        __syncthreads();
    }
    const int base = ps[t] - s;
    #pragma unroll
    for (int u = 0; u < 8; ++u) {
        int i = i0 + u;
        if (i < n) offsets[i] = base + loc[u];
    }
    if (t == 255) bsum[blockIdx.x] = ps[255];
}

__global__ void scanB(int* __restrict__ bsum, int nb)
{
    // single-wave shuffle exclusive scan (nb <= 64)
    const int t = threadIdx.x;
    int v = (t < nb) ? bsum[t] : 0;
    int inc = v;
    #pragma unroll
    for (int off = 1; off < 64; off <<= 1) {
        int u = __shfl_up(inc, off, 64);
        if (t >= off) inc += u;
    }
    if (t < nb) bsum[t] = inc - v;   // exclusive
}

__global__ __launch_bounds__(256) void scanC(
    const int* __restrict__ bsum, int* __restrict__ offsets,
    int* __restrict__ cursor, int n)
{
    const int i0 = blockIdx.x * SCB + threadIdx.x * 8;
    const int add = bsum[blockIdx.x];
    #pragma unroll
    for (int u = 0; u < 8; ++u) {
        int i = i0 + u;
        if (i < n) { int o = offsets[i] + add; offsets[i] = o; cursor[i] = o; }
    }
}

// ---------------------------------------------------------------------------
// Reorder edges into dst-node order, dst-range partitioned (R6-verified:
// epack/cursor lines single-XCD, WRITE_SIZE collapse).
// pack = src(16b) | seg(8b)<<16.
// ---------------------------------------------------------------------------
__global__ __launch_bounds__(256) void reorder_kernel(
    const int* __restrict__ ei, const int* __restrict__ batch,
    int* __restrict__ cursor, unsigned* __restrict__ epack,
    int E, int N, int nspan)
{
    const int p  = blockIdx.x & 7;
    const int ci = blockIdx.x >> 3;
    const int lo = p * nspan;
    const int hi = min(N, lo + nspan);
    const int e0 = ci * 1024 + threadIdx.x * 4;

    int d[4];
    if (e0 + 3 < E) {
        const int4 d4 = *(const int4*)(ei + E + e0);
        d[0] = d4.x; d[1] = d4.y; d[2] = d4.z; d[3] = d4.w;
    } else {
        #pragma unroll
        for (int u = 0; u < 4; ++u)
            d[u] = (e0 + u < E) ? ei[E + e0 + u] : -1;   // -1: never in span
    }

    #pragma unroll
    for (int u = 0; u < 4; ++u) {
        const int dst = min(max(d[u], 0), N - 1);
        if (d[u] >= 0 && dst >= lo && dst < hi) {
            int src = ei[e0 + u];
            src = min(max(src, 0), N - 1);
            int seg = batch[src];
            seg = min(max(seg, 0), NSEG - 1);
            const int pos = atomicAdd(&cursor[dst], 1);
            epack[pos] = (unsigned)src | ((unsigned)seg << 16);
        }
    }
}

// ---------------------------------------------------------------------------
// Score: persistent grid, one wave per dst node; q[dst] in registers across
// its edges; 4 edges in flight (16-lane groups, float4 k gathers, 4-step
// shuffle reduce).  Per-block LDS denom histogram flushed once into the
// block's XCD-private denom copy.
// ---------------------------------------------------------------------------
__global__ __launch_bounds__(256) void score_kernel(
    const float* __restrict__ q, const float* __restrict__ k,
    const unsigned* __restrict__ epack,
    const int* __restrict__ offsets, const int* __restrict__ counts,
    float* __restrict__ exps, float* __restrict__ denom8, int N)
{
    __shared__ float sden[NSEG];
    const int t = threadIdx.x;
    sden[t] = 0.f;
    __syncthreads();

    const int lane16 = t & 15;
    const int grp    = (t >> 4) & 3;
    const int wave   = t >> 6;
    const int nwaves = gridDim.x * 4;

    const float4* q4 = (const float4*)q;
    const float4* k4 = (const float4*)k;

    for (int n = blockIdx.x * 4 + wave; n < N; n += nwaves) {
        const int off = offsets[n];
        const int cnt = counts[n];
        if (cnt == 0) continue;
        const float4 qv = q4[(size_t)n * 16 + lane16];
        for (int i = grp; i < cnt; i += 4) {
            const int pos = off + i;
            const unsigned p = epack[pos];
            const int src = p & 0xFFFF;
            const float4 kv = k4[(size_t)src * 16 + lane16];
            float d = kv.x * qv.x + kv.y * qv.y + kv.z * qv.z + kv.w * qv.w;
            d += __shfl_xor(d, 1, 64);
            d += __shfl_xor(d, 2, 64);
            d += __shfl_xor(d, 4, 64);
            d += __shfl_xor(d, 8, 64);
            if (lane16 == 0) {
                float ex = __expf(d * 0.125f);
                exps[pos] = ex;
                atomicAdd(&sden[(p >> 16) & 255], ex);
            }
        }
    }
    __syncthreads();
    float ds = sden[t];
    if (ds != 0.f) atomicAdd(&denom8[(blockIdx.x & 7) * NSEG + t], ds);
}

// ---------------------------------------------------------------------------
// Accumulate: one wave per dst node, lane = feature, register accumulator,
// zero atomics.  LDS reciprocal table built by summing the 8 denom copies.
// ---------------------------------------------------------------------------
__global__ __launch_bounds__(256) void accum_kernel(
    const float* __restrict__ v, const float* __restrict__ exps,
    const unsigned* __restrict__ epack,
    const int* __restrict__ offsets, const int* __restrict__ counts,
    const float* __restrict__ denom8, float* __restrict__ out, int N)
{
    __shared__ float rden[NSEG];
    const int t = threadIdx.x;
    {
        float dsum = 0.f;
        #pragma unroll
        for (int p = 0; p < 8; ++p) dsum += denom8[p * NSEG + t];
        rden[t] = 1.0f / (dsum + 1e-6f);
    }
    __syncthreads();

    const int lane = t & 63;
    const int wave = t >> 6;
    const int n = blockIdx.x * 4 + wave;
    if (n >= N) return;

    const int off = offsets[n];
    const int cnt = counts[n];

    float acc = 0.f;
    int i = 0;
    for (; i + 8 <= cnt; i += 8) {
        const uint4  pa = *(const uint4*)(epack + off + i);
        const uint4  pb = *(const uint4*)(epack + off + i + 4);
        const float4 ea = *(const float4*)(exps + off + i);
        const float4 eb = *(const float4*)(exps + off + i + 4);
        const float v0 = v[(size_t)(pa.x & 0xFFFF) * H + lane];
        const float v1 = v[(size_t)(pa.y & 0xFFFF) * H + lane];
        const float v2 = v[(size_t)(pa.z & 0xFFFF) * H + lane];
        const float v3 = v[(size_t)(pa.w & 0xFFFF) * H + lane];
        const float v4_ = v[(size_t)(pb.x & 0xFFFF) * H + lane];
        const float v5 = v[(size_t)(pb.y & 0xFFFF) * H + lane];
        const float v6 = v[(size_t)(pb.z & 0xFFFF) * H + lane];
        const float v7 = v[(size_t)(pb.w & 0xFFFF) * H + lane];
        acc = fmaf(v0, ea.x * rden[(pa.x >> 16) & 255], acc);
        acc = fmaf(v1, ea.y * rden[(pa.y >> 16) & 255], acc);
        acc = fmaf(v2, ea.z * rden[(pa.z >> 16) & 255], acc);
        acc = fmaf(v3, ea.w * rden[(pa.w >> 16) & 255], acc);
        acc = fmaf(v4_, eb.x * rden[(pb.x >> 16) & 255], acc);
        acc = fmaf(v5, eb.y * rden[(pb.y >> 16) & 255], acc);
        acc = fmaf(v6, eb.z * rden[(pb.z >> 16) & 255], acc);
        acc = fmaf(v7, eb.w * rden[(pb.w >> 16) & 255], acc);
    }
    for (; i + 4 <= cnt; i += 4) {
        const uint4  pp = *(const uint4*)(epack + off + i);
        const float4 ee = *(const float4*)(exps + off + i);
        const float v0 = v[(size_t)(pp.x & 0xFFFF) * H + lane];
        const float v1 = v[(size_t)(pp.y & 0xFFFF) * H + lane];
        const float v2 = v[(size_t)(pp.z & 0xFFFF) * H + lane];
        const float v3 = v[(size_t)(pp.w & 0xFFFF) * H + lane];
        acc = fmaf(v0, ee.x * rden[(pp.x >> 16) & 255], acc);
        acc = fmaf(v1, ee.y * rden[(pp.y >> 16) & 255], acc);
        acc = fmaf(v2, ee.z * rden[(pp.z >> 16) & 255], acc);
        acc = fmaf(v3, ee.w * rden[(pp.w >> 16) & 255], acc);
    }
    for (; i < cnt; ++i) {
        const unsigned p = epack[off + i];
        acc = fmaf(v[(size_t)(p & 0xFFFF) * H + lane],
                   exps[off + i] * rden[(p >> 16) & 255], acc);
    }
    out[(size_t)n * H + lane] = acc;
}

extern "C" void kernel_launch(void* const* d_in, const int* in_sizes, int n_in,
                              void* d_out, int out_size, void* d_ws, size_t ws_size,
                              hipStream_t stream)
{
    const float* x   = (const float*)d_in[0];
    const float* Wq  = (const float*)d_in[1];
    const float* bq  = (const float*)d_in[2];
    const float* Wk  = (const float*)d_in[3];
    const float* bk  = (const float*)d_in[4];
    const float* Wv  = (const float*)d_in[5];
    const float* bv  = (const float*)d_in[6];
    const int* ei    = (const int*)d_in[7];
    const int* batch = (const int*)d_in[8];

    const int N = in_sizes[8];        // 50000
    const int E = in_sizes[7] / 2;    // 800000
    const int EP = E + 3 * N + 16;    // padded edge-slot capacity

    float*    q       = (float*)d_ws;
    float*    k       = q + (size_t)N * H;
    float*    v       = k + (size_t)N * H;
    float*    exps    = v + (size_t)N * H;
    unsigned* epack   = (unsigned*)(exps + EP);
    int*      counts  = (int*)(epack + EP);
    int*      offsets = counts + N;
    int*      cursor  = offsets + N;
    int*      bsum    = cursor + N;
    float*    denom8  = (float*)(bsum + 64);

    hipMemsetAsync(counts, 0, N * sizeof(int), stream);
    hipMemsetAsync(denom8, 0, 8 * NSEG * sizeof(float), stream);

    const int NT    = (N + MB - 1) / MB;     // 782 row tiles
    const int NC    = (E + 1023) / 1024;     // 782 edge chunks
    const int nspan = (N + 7) / 8;           // dst-range span per XCD class
    const int NBSC  = (N + SCB - 1) / SCB;   // 25 scan blocks

    hist_kernel<<<8 * NC, 256, 0, stream>>>(ei, counts, N, E, nspan);

    qkv_mfma<<<512, 768, 0, stream>>>(
        x, Wq, Wk, Wv, bq, bk, bv, q, k, v, N, NT);

    scanA<<<NBSC, 256, 0, stream>>>(counts, offsets, bsum, N);
    scanB<<<1, 64, 0, stream>>>(bsum, NBSC);
    scanC<<<NBSC, 256, 0, stream>>>(bsum, offsets, cursor, N);

    reorder_kernel<<<8 * NC, 256, 0, stream>>>(
        ei, batch, cursor, epack, E, N, nspan);

    score_kernel<<<2048, 256, 0, stream>>>(
        q, k, epack, offsets, counts, exps, denom8, N);

    accum_kernel<<<(N + 3) / 4, 256, 0, stream>>>(
        v, exps, epack, offsets, counts, denom8, (float*)d_out, N);
}

// Round 8
// 281.304 us; speedup vs baseline: 1.1588x; 1.0062x over previous
//
#include <hip/hip_runtime.h>

#define H    64
#define F    256
#define NSEG 256
#define SCB  2048   // scan elements per block
#define MB   64     // qkv node rows per tile
#define KC   64     // qkv K chunk
#define XPAD 72     // LDS row stride in shorts (64 + 8: 16B-aligned, odd 16B-stride)

typedef float          f32x4v __attribute__((ext_vector_type(4)));
typedef short          bf16x8 __attribute__((ext_vector_type(8)));
typedef unsigned short u16x4  __attribute__((ext_vector_type(4)));

// ---------------------------------------------------------------------------
// QKV GEMM, persistent-W, WITH fused in-degree histogram.
// R7 post-mortem: 2 blocks/CU never co-scheduled (occupancy pinned at 23%);
// qkv has idle issue capacity at 1 block/CU.  The standalone hist (~20-30us)
// is pure atomic/latency work; since R6's dst-range partitioning its counts
// lines are XCD-local L2 (25 KB hot set per XCD - survives the x stream),
// so its atomics drain in ~200cy and can ride inside qkv's stalls (the R0
// fusion, with the cross-XCD line-bouncing disease cured).
// Block b (of 512): hist class p=b&7 (XCD-aligned), edge window m=b>>3 of 64.
//   acc += xh*wh + xh*wl + xl*wh    (xl*wl ~ 2^-17 dropped)
// ---------------------------------------------------------------------------
#define CVT_WRITE(buf, rr, cc, val) do {                                      \
    const float ff_[4] = {(val).x, (val).y, (val).z, (val).w};                \
    u16x4 h_, l_;                                                             \
    _Pragma("unroll")                                                         \
    for (int u_ = 0; u_ < 4; ++u_) {                                          \
        unsigned ub_ = __float_as_uint(ff_[u_]);                              \
        h_[u_] = (unsigned short)(ub_ >> 16);                                 \
        float rf_ = ff_[u_] - __uint_as_float(ub_ & 0xFFFF0000u);             \
        l_[u_] = (unsigned short)(__float_as_uint(rf_) >> 16);                \
    }                                                                         \
    *(u16x4*)&xs_hi[buf][(rr) * XPAD + (cc) * 4] = h_;                        \
    *(u16x4*)&xs_lo[buf][(rr) * XPAD + (cc) * 4] = l_;                        \
} while (0)

__global__ __launch_bounds__(768, 3) void qkv_mfma(
    const float* __restrict__ x,
    const float* __restrict__ Wq, const float* __restrict__ Wk,
    const float* __restrict__ Wv,
    const float* __restrict__ bq, const float* __restrict__ bk,
    const float* __restrict__ bv,
    float* __restrict__ q, float* __restrict__ k, float* __restrict__ v,
    const int* __restrict__ ei, int* __restrict__ counts,
    int N, int E, int nspan, int ntiles)
{
    __shared__ unsigned short xs_hi[2][MB * XPAD];   // 2 x 9216 B
    __shared__ unsigned short xs_lo[2][MB * XPAD];   // 2 x 9216 B

    const int t = threadIdx.x;

    // --- fused histogram: dst-range partitioned, L2-local atomics ---
    // (issued first; drains during W preload + prologue staging)
    {
        const int p  = blockIdx.x & 7;           // span class == XCD
        const int m  = blockIdx.x >> 3;          // 0..63 edge window
        const int lo = p * nspan;
        const int hi = min(N, lo + nspan);
        const int eb = (E + 63) >> 6;            // edges per window
        const int e1 = min(E, (m + 1) * eb);
        #pragma unroll 4
        for (int e = m * eb + t; e < e1; e += 768) {
            const int d = min(max(ei[E + e], 0), N - 1);
            if (d >= lo && d < hi) atomicAdd(&counts[d], 1);
        }
    }

    const int lane = t & 63;
    const int w    = t >> 6;        // 0..11
    const int mat  = w >> 2;        // 0..2  (Q,K,V)
    const int ct   = w & 3;         // 16-col tile
    const int l15  = lane & 15;
    const int quad = lane >> 4;

    const float* Wm   = (mat == 0) ? Wq : (mat == 1) ? Wk : Wv;
    const float* bias = (mat == 0) ? bq : (mat == 1) ? bk : bv;
    float*       dst  = (mat == 0) ? q  : (mat == 1) ? k  : v;
    const int col = ct * 16 + l15;
    const float bb = bias[col];

    // ---- W preload: full-K B fragments in registers, split hi/lo in-reg ---
    bf16x8 Bh[8], Bl[8];
    #pragma unroll
    for (int u = 0; u < 8; ++u) {
        #pragma unroll
        for (int j = 0; j < 8; ++j) {
            const float f = Wm[(size_t)(u * 32 + quad * 8 + j) * H + col];
            const unsigned ub = __float_as_uint(f);
            Bh[u][j] = (short)(ub >> 16);
            const float rf = f - __uint_as_float(ub & 0xFFFF0000u);
            Bl[u][j] = (short)(__float_as_uint(rf) >> 16);
        }
    }

    // staging slots: 1024 float4 per chunk; thread t does slot t (always)
    // and slot t+768 (t<256).  (t+768)&15 == t&15 since 768 % 16 == 0.
    const int r0 = t >> 4;
    const int c0 = t & 15;
    const int r1 = (t + 768) >> 4;

    #pragma unroll 1
    for (int tile = blockIdx.x; tile < ntiles; tile += gridDim.x) {
        const int block0 = tile * MB;

        f32x4v acc[4];
        #pragma unroll
        for (int i = 0; i < 4; ++i) acc[i] = (f32x4v)0.f;

        // ---- prologue: chunk 0 into buffer 0 ----
        float4 pv0, pv1;
        pv0 = *(const float4*)(x + (size_t)min(block0 + r0, N - 1) * F + c0 * 4);
        if (t < 256)
            pv1 = *(const float4*)(x + (size_t)min(block0 + r1, N - 1) * F + c0 * 4);
        CVT_WRITE(0, r0, c0, pv0);
        if (t < 256) CVT_WRITE(0, r1, c0, pv1);

        #pragma unroll
        for (int c = 0; c < 4; ++c) {
            __syncthreads();          // buf[c&1] writes visible to all waves

            // issue next chunk's loads EARLY (consumed after the MFMAs)
            if (c < 3) {
                const int kb = (c + 1) * KC;
                pv0 = *(const float4*)(x + (size_t)min(block0 + r0, N - 1) * F + kb + c0 * 4);
                if (t < 256)
                    pv1 = *(const float4*)(x + (size_t)min(block0 + r1, N - 1) * F + kb + c0 * 4);
            }

            // MFMA burst on buf[c&1]; B frags from registers (u = c*2+sk)
            #pragma unroll
            for (int sk = 0; sk < 2; ++sk) {
                const int u = c * 2 + sk;
                #pragma unroll
                for (int mt = 0; mt < 4; ++mt) {
                    const int ao = (mt * 16 + l15) * XPAD + sk * 32 + quad * 8;
                    const bf16x8 ah = *(const bf16x8*)&xs_hi[c & 1][ao];
                    const bf16x8 al = *(const bf16x8*)&xs_lo[c & 1][ao];
                    f32x4v a = acc[mt];
                    a = __builtin_amdgcn_mfma_f32_16x16x32_bf16(ah, Bh[u], a, 0, 0, 0);
                    a = __builtin_amdgcn_mfma_f32_16x16x32_bf16(ah, Bl[u], a, 0, 0, 0);
                    a = __builtin_amdgcn_mfma_f32_16x16x32_bf16(al, Bh[u], a, 0, 0, 0);
                    acc[mt] = a;
                }
            }

            // convert + write next chunk into the other buffer (WAR-safe:
            // buf[nxt] last read in chunk c-1, all waves past top-of-c barrier)
            if (c < 3) {
                const int nb = (c & 1) ^ 1;
                CVT_WRITE(nb, r0, c0, pv0);
                if (t < 256) CVT_WRITE(nb, r1, c0, pv1);
            }
        }

        // epilogue: C layout col = lane&15, row = quad*4 + reg (m89-verified)
        #pragma unroll
        for (int mt = 0; mt < 4; ++mt) {
            #pragma unroll
            for (int r = 0; r < 4; ++r) {
                const int node = block0 + mt * 16 + quad * 4 + r;
                if (node < N)
                    dst[(size_t)node * H + col] = acc[mt][r] + bb;
            }
        }
    }
}

// ---------------------------------------------------------------------------
// Scan phase A/B/C: exclusive scan of padded (x4) per-node counts.
// ---------------------------------------------------------------------------
__global__ __launch_bounds__(256) void scanA(
    const int* __restrict__ counts, int* __restrict__ offsets,
    int* __restrict__ bsum, int n)
{
    __shared__ int ps[256];
    const int t = threadIdx.x;
    const int i0 = blockIdx.x * SCB + t * 8;
    int loc[8];
    int s = 0;
    #pragma unroll
    for (int u = 0; u < 8; ++u) {
        int i = i0 + u;
        int c = (i < n) ? ((counts[i] + 3) & ~3) : 0;
        loc[u] = s; s += c;
    }
    ps[t] = s;
    __syncthreads();
    for (int off = 1; off < 256; off <<= 1) {
        int a = (t >= off) ? ps[t - off] : 0;
        __syncthreads();
        ps[t] += a;
        __syncthreads();
    }
    const int base = ps[t] - s;
    #pragma unroll
    for (int u = 0; u < 8; ++u) {
        int i = i0 + u;
        if (i < n) offsets[i] = base + loc[u];
    }
    if (t == 255) bsum[blockIdx.x] = ps[255];
}

__global__ void scanB(int* __restrict__ bsum, int nb)
{
    // single-wave shuffle exclusive scan (nb <= 64)
    const int t = threadIdx.x;
    int v = (t < nb) ? bsum[t] : 0;
    int inc = v;
    #pragma unroll
    for (int off = 1; off < 64; off <<= 1) {
        int u = __shfl_up(inc, off, 64);
        if (t >= off) inc += u;
    }
    if (t < nb) bsum[t] = inc - v;   // exclusive
}

__global__ __launch_bounds__(256) void scanC(
    const int* __restrict__ bsum, int* __restrict__ offsets,
    int* __restrict__ cursor, int n)
{
    const int i0 = blockIdx.x * SCB + threadIdx.x * 8;
    const int add = bsum[blockIdx.x];
    #pragma unroll
    for (int u = 0; u < 8; ++u) {
        int i = i0 + u;
        if (i < n) { int o = offsets[i] + add; offsets[i] = o; cursor[i] = o; }
    }
}

// ---------------------------------------------------------------------------
// Reorder edges into dst-node order, dst-range partitioned (R6-verified:
// epack/cursor lines single-XCD, WRITE_SIZE collapse).
// pack = src(16b) | seg(8b)<<16.
// ---------------------------------------------------------------------------
__global__ __launch_bounds__(256) void reorder_kernel(
    const int* __restrict__ ei, const int* __restrict__ batch,
    int* __restrict__ cursor, unsigned* __restrict__ epack,
    int E, int N, int nspan)
{
    const int p  = blockIdx.x & 7;
    const int ci = blockIdx.x >> 3;
    const int lo = p * nspan;
    const int hi = min(N, lo + nspan);
    const int e0 = ci * 1024 + threadIdx.x * 4;

    int d[4];
    if (e0 + 3 < E) {
        const int4 d4 = *(const int4*)(ei + E + e0);
        d[0] = d4.x; d[1] = d4.y; d[2] = d4.z; d[3] = d4.w;
    } else {
        #pragma unroll
        for (int u = 0; u < 4; ++u)
            d[u] = (e0 + u < E) ? ei[E + e0 + u] : -1;   // -1: never in span
    }

    #pragma unroll
    for (int u = 0; u < 4; ++u) {
        const int dst = min(max(d[u], 0), N - 1);
        if (d[u] >= 0 && dst >= lo && dst < hi) {
            int src = ei[e0 + u];
            src = min(max(src, 0), N - 1);
            int seg = batch[src];
            seg = min(max(seg, 0), NSEG - 1);
            const int pos = atomicAdd(&cursor[dst], 1);
            epack[pos] = (unsigned)src | ((unsigned)seg << 16);
        }
    }
}

// ---------------------------------------------------------------------------
// Score: persistent grid, one wave per dst node; q[dst] in registers across
// its edges; 4 edges in flight (16-lane groups, float4 k gathers, 4-step
// shuffle reduce).  Per-block LDS denom histogram flushed once into the
// block's XCD-private denom copy.
// ---------------------------------------------------------------------------
__global__ __launch_bounds__(256) void score_kernel(
    const float* __restrict__ q, const float* __restrict__ k,
    const unsigned* __restrict__ epack,
    const int* __restrict__ offsets, const int* __restrict__ counts,
    float* __restrict__ exps, float* __restrict__ denom8, int N)
{
    __shared__ float sden[NSEG];
    const int t = threadIdx.x;
    sden[t] = 0.f;
    __syncthreads();

    const int lane16 = t & 15;
    const int grp    = (t >> 4) & 3;
    const int wave   = t >> 6;
    const int nwaves = gridDim.x * 4;

    const float4* q4 = (const float4*)q;
    const float4* k4 = (const float4*)k;

    for (int n = blockIdx.x * 4 + wave; n < N; n += nwaves) {
        const int off = offsets[n];
        const int cnt = counts[n];
        if (cnt == 0) continue;
        const float4 qv = q4[(size_t)n * 16 + lane16];
        for (int i = grp; i < cnt; i += 4) {
            const int pos = off + i;
            const unsigned p = epack[pos];
            const int src = p & 0xFFFF;
            const float4 kv = k4[(size_t)src * 16 + lane16];
            float d = kv.x * qv.x + kv.y * qv.y + kv.z * qv.z + kv.w * qv.w;
            d += __shfl_xor(d, 1, 64);
            d += __shfl_xor(d, 2, 64);
            d += __shfl_xor(d, 4, 64);
            d += __shfl_xor(d, 8, 64);
            if (lane16 == 0) {
                float ex = __expf(d * 0.125f);
                exps[pos] = ex;
                atomicAdd(&sden[(p >> 16) & 255], ex);
            }
        }
    }
    __syncthreads();
    float ds = sden[t];
    if (ds != 0.f) atomicAdd(&denom8[(blockIdx.x & 7) * NSEG + t], ds);
}

// ---------------------------------------------------------------------------
// Accumulate: one wave per dst node, lane = feature, register accumulator,
// zero atomics.  LDS reciprocal table built by summing the 8 denom copies.
// ---------------------------------------------------------------------------
__global__ __launch_bounds__(256) void accum_kernel(
    const float* __restrict__ v, const float* __restrict__ exps,
    const unsigned* __restrict__ epack,
    const int* __restrict__ offsets, const int* __restrict__ counts,
    const float* __restrict__ denom8, float* __restrict__ out, int N)
{
    __shared__ float rden[NSEG];
    const int t = threadIdx.x;
    {
        float dsum = 0.f;
        #pragma unroll
        for (int p = 0; p < 8; ++p) dsum += denom8[p * NSEG + t];
        rden[t] = 1.0f / (dsum + 1e-6f);
    }
    __syncthreads();

    const int lane = t & 63;
    const int wave = t >> 6;
    const int n = blockIdx.x * 4 + wave;
    if (n >= N) return;

    const int off = offsets[n];
    const int cnt = counts[n];

    float acc = 0.f;
    int i = 0;
    for (; i + 8 <= cnt; i += 8) {
        const uint4  pa = *(const uint4*)(epack + off + i);
        const uint4  pb = *(const uint4*)(epack + off + i + 4);
        const float4 ea = *(const float4*)(exps + off + i);
        const float4 eb = *(const float4*)(exps + off + i + 4);
        const float v0 = v[(size_t)(pa.x & 0xFFFF) * H + lane];
        const float v1 = v[(size_t)(pa.y & 0xFFFF) * H + lane];
        const float v2 = v[(size_t)(pa.z & 0xFFFF) * H + lane];
        const float v3 = v[(size_t)(pa.w & 0xFFFF) * H + lane];
        const float v4_ = v[(size_t)(pb.x & 0xFFFF) * H + lane];
        const float v5 = v[(size_t)(pb.y & 0xFFFF) * H + lane];
        const float v6 = v[(size_t)(pb.z & 0xFFFF) * H + lane];
        const float v7 = v[(size_t)(pb.w & 0xFFFF) * H + lane];
        acc = fmaf(v0, ea.x * rden[(pa.x >> 16) & 255], acc);
        acc = fmaf(v1, ea.y * rden[(pa.y >> 16) & 255], acc);
        acc = fmaf(v2, ea.z * rden[(pa.z >> 16) & 255], acc);
        acc = fmaf(v3, ea.w * rden[(pa.w >> 16) & 255], acc);
        acc = fmaf(v4_, eb.x * rden[(pb.x >> 16) & 255], acc);
        acc = fmaf(v5, eb.y * rden[(pb.y >> 16) & 255], acc);
        acc = fmaf(v6, eb.z * rden[(pb.z >> 16) & 255], acc);
        acc = fmaf(v7, eb.w * rden[(pb.w >> 16) & 255], acc);
    }
    for (; i + 4 <= cnt; i += 4) {
        const uint4  pp = *(const uint4*)(epack + off + i);
        const float4 ee = *(const float4*)(exps + off + i);
        const float v0 = v[(size_t)(pp.x & 0xFFFF) * H + lane];
        const float v1 = v[(size_t)(pp.y & 0xFFFF) * H + lane];
        const float v2 = v[(size_t)(pp.z & 0xFFFF) * H + lane];
        const float v3 = v[(size_t)(pp.w & 0xFFFF) * H + lane];
        acc = fmaf(v0, ee.x * rden[(pp.x >> 16) & 255], acc);
        acc = fmaf(v1, ee.y * rden[(pp.y >> 16) & 255], acc);
        acc = fmaf(v2, ee.z * rden[(pp.z >> 16) & 255], acc);
        acc = fmaf(v3, ee.w * rden[(pp.w >> 16) & 255], acc);
    }
    for (; i < cnt; ++i) {
        const unsigned p = epack[off + i];
        acc = fmaf(v[(size_t)(p & 0xFFFF) * H + lane],
                   exps[off + i] * rden[(p >> 16) & 255], acc);
    }
    out[(size_t)n * H + lane] = acc;
}

extern "C" void kernel_launch(void* const* d_in, const int* in_sizes, int n_in,
                              void* d_out, int out_size, void* d_ws, size_t ws_size,
                              hipStream_t stream)
{
    const float* x   = (const float*)d_in[0];
    const float* Wq  = (const float*)d_in[1];
    const float* bq  = (const float*)d_in[2];
    const float* Wk  = (const float*)d_in[3];
    const float* bk  = (const float*)d_in[4];
    const float* Wv  = (const float*)d_in[5];
    const float* bv  = (const float*)d_in[6];
    const int* ei    = (const int*)d_in[7];
    const int* batch = (const int*)d_in[8];

    const int N = in_sizes[8];        // 50000
    const int E = in_sizes[7] / 2;    // 800000
    const int EP = E + 3 * N + 16;    // padded edge-slot capacity

    float*    q       = (float*)d_ws;
    float*    k       = q + (size_t)N * H;
    float*    v       = k + (size_t)N * H;
    float*    exps    = v + (size_t)N * H;
    unsigned* epack   = (unsigned*)(exps + EP);
    int*      counts  = (int*)(epack + EP);
    int*      offsets = counts + N;
    int*      cursor  = offsets + N;
    int*      bsum    = cursor + N;
    float*    denom8  = (float*)(bsum + 64);

    hipMemsetAsync(counts, 0, N * sizeof(int), stream);
    hipMemsetAsync(denom8, 0, 8 * NSEG * sizeof(float), stream);

    const int NT    = (N + MB - 1) / MB;     // 782 row tiles
    const int NC    = (E + 1023) / 1024;     // 782 edge chunks
    const int nspan = (N + 7) / 8;           // dst-range span per XCD class
    const int NBSC  = (N + SCB - 1) / SCB;   // 25 scan blocks

    qkv_mfma<<<512, 768, 0, stream>>>(
        x, Wq, Wk, Wv, bq, bk, bv, q, k, v, ei, counts, N, E, nspan, NT);

    scanA<<<NBSC, 256, 0, stream>>>(counts, offsets, bsum, N);
    scanB<<<1, 64, 0, stream>>>(bsum, NBSC);
    scanC<<<NBSC, 256, 0, stream>>>(bsum, offsets, cursor, N);

    reorder_kernel<<<8 * NC, 256, 0, stream>>>(
        ei, batch, cursor, epack, E, N, nspan);

    score_kernel<<<2048, 256, 0, stream>>>(
        q, k, epack, offsets, counts, exps, denom8, N);

    accum_kernel<<<(N + 3) / 4, 256, 0, stream>>>(
        v, exps, epack, offsets, counts, denom8, (float*)d_out, N);
}

// Round 9
// 267.909 us; speedup vs baseline: 1.2167x; 1.0500x over previous
//
#include <hip/hip_runtime.h>

#define H    64
#define F    256
#define NSEG 256
#define SCB  2048   // scan elements per block
#define MB   64     // qkv node rows per tile
#define KC   64     // qkv K chunk
#define XPAD 72     // LDS row stride in shorts (64 + 8: 16B-aligned, odd 16B-stride)
#define NSPAN_MAX 8192

typedef float          f32x4v __attribute__((ext_vector_type(4)));
typedef short          bf16x8 __attribute__((ext_vector_type(8)));
typedef unsigned short u16x4  __attribute__((ext_vector_type(4)));

// ---------------------------------------------------------------------------
// In-degree histogram v3: LDS-privatized, ZERO global atomics.
// R8 post-mortem: global-atomic hist costs ~25us standalone (L2 RMW rate)
// and ~27us fused (stream eviction -> HBM RMW + barrier drain).  Fix: span
// partition makes the per-block histogram fit LDS (nspan=6250 = 25KB).
// Grid = 8 spans x 8 chunks.  Block (p,c): zero LDS hist; scan chunk c of
// the dst array; LDS-atomic the in-span hits; write the hist NON-atomically
// to counts8[c][span range].  Each copy c is fully covered across the 8
// span-blocks of chunk c; scanA sums the 8 copies.  Cost: 8x re-read of
// the dst array (25.6 MB, L3-hot) -- traded against 800K L2 atomics.
// ---------------------------------------------------------------------------
__global__ __launch_bounds__(1024) void hist8_kernel(
    const int* __restrict__ ei, int* __restrict__ counts8,
    int N, int E, int nspan)
{
    __shared__ int lh[NSPAN_MAX];
    const int p  = blockIdx.x & 7;           // span class
    const int c  = blockIdx.x >> 3;          // edge chunk 0..7
    const int lo = p * nspan;
    const int span = min(N - lo, nspan);
    const int t = threadIdx.x;

    for (int i = t; i < span; i += 1024) lh[i] = 0;
    __syncthreads();

    const int epc = (E + 7) >> 3;            // edges per chunk
    const int e0 = c * epc;
    const int e1 = min(E, e0 + epc);

    if (((E + e0) & 3) == 0) {               // 16B-aligned vector path
        const int nv = (e1 - e0) >> 2;
        for (int i = t; i < nv; i += 1024) {
            const int4 d4 = *(const int4*)(ei + E + e0 + i * 4);
            int d;
            d = min(max(d4.x, 0), N - 1) - lo; if ((unsigned)d < (unsigned)span) atomicAdd(&lh[d], 1);
            d = min(max(d4.y, 0), N - 1) - lo; if ((unsigned)d < (unsigned)span) atomicAdd(&lh[d], 1);
            d = min(max(d4.z, 0), N - 1) - lo; if ((unsigned)d < (unsigned)span) atomicAdd(&lh[d], 1);
            d = min(max(d4.w, 0), N - 1) - lo; if ((unsigned)d < (unsigned)span) atomicAdd(&lh[d], 1);
        }
        for (int e = e0 + nv * 4 + t; e < e1; e += 1024) {
            const int d = min(max(ei[E + e], 0), N - 1) - lo;
            if ((unsigned)d < (unsigned)span) atomicAdd(&lh[d], 1);
        }
    } else {
        for (int e = e0 + t; e < e1; e += 1024) {
            const int d = min(max(ei[E + e], 0), N - 1) - lo;
            if ((unsigned)d < (unsigned)span) atomicAdd(&lh[d], 1);
        }
    }
    __syncthreads();

    // non-atomic flush: copy c, span slice [lo, lo+span)
    for (int i = t; i < span; i += 1024) counts8[(size_t)c * N + lo + i] = lh[i];
}

// ---------------------------------------------------------------------------
// QKV GEMM, persistent-W (R6-measured-best form: no atomics, grid 256).
// 12 waves; wave = (mat, 16-col tile); full-K B operand in 64 VGPRs, split
// from raw f32 W once per block.  Double-buffered LDS staging of x hi/lo,
// async-split (issue loads early, convert+ds_write after MFMAs), one
// barrier per K-chunk.
//   acc += xh*wh + xh*wl + xl*wh    (xl*wl ~ 2^-17 dropped)
// ---------------------------------------------------------------------------
#define CVT_WRITE(buf, rr, cc, val) do {                                      \
    const float ff_[4] = {(val).x, (val).y, (val).z, (val).w};                \
    u16x4 h_, l_;                                                             \
    _Pragma("unroll")                                                         \
    for (int u_ = 0; u_ < 4; ++u_) {                                          \
        unsigned ub_ = __float_as_uint(ff_[u_]);                              \
        h_[u_] = (unsigned short)(ub_ >> 16);                                 \
        float rf_ = ff_[u_] - __uint_as_float(ub_ & 0xFFFF0000u);             \
        l_[u_] = (unsigned short)(__float_as_uint(rf_) >> 16);                \
    }                                                                         \
    *(u16x4*)&xs_hi[buf][(rr) * XPAD + (cc) * 4] = h_;                        \
    *(u16x4*)&xs_lo[buf][(rr) * XPAD + (cc) * 4] = l_;                        \
} while (0)

__global__ __launch_bounds__(768, 3) void qkv_mfma(
    const float* __restrict__ x,
    const float* __restrict__ Wq, const float* __restrict__ Wk,
    const float* __restrict__ Wv,
    const float* __restrict__ bq, const float* __restrict__ bk,
    const float* __restrict__ bv,
    float* __restrict__ q, float* __restrict__ k, float* __restrict__ v,
    int N, int ntiles)
{
    __shared__ unsigned short xs_hi[2][MB * XPAD];   // 2 x 9216 B
    __shared__ unsigned short xs_lo[2][MB * XPAD];   // 2 x 9216 B

    const int t    = threadIdx.x;
    const int lane = t & 63;
    const int w    = t >> 6;        // 0..11
    const int mat  = w >> 2;        // 0..2  (Q,K,V)
    const int ct   = w & 3;         // 16-col tile
    const int l15  = lane & 15;
    const int quad = lane >> 4;

    const float* Wm   = (mat == 0) ? Wq : (mat == 1) ? Wk : Wv;
    const float* bias = (mat == 0) ? bq : (mat == 1) ? bk : bv;
    float*       dst  = (mat == 0) ? q  : (mat == 1) ? k  : v;
    const int col = ct * 16 + l15;
    const float bb = bias[col];

    // ---- W preload: full-K B fragments in registers, split hi/lo in-reg ---
    bf16x8 Bh[8], Bl[8];
    #pragma unroll
    for (int u = 0; u < 8; ++u) {
        #pragma unroll
        for (int j = 0; j < 8; ++j) {
            const float f = Wm[(size_t)(u * 32 + quad * 8 + j) * H + col];
            const unsigned ub = __float_as_uint(f);
            Bh[u][j] = (short)(ub >> 16);
            const float rf = f - __uint_as_float(ub & 0xFFFF0000u);
            Bl[u][j] = (short)(__float_as_uint(rf) >> 16);
        }
    }

    // staging slots: 1024 float4 per chunk; thread t does slot t (always)
    // and slot t+768 (t<256).  (t+768)&15 == t&15 since 768 % 16 == 0.
    const int r0 = t >> 4;
    const int c0 = t & 15;
    const int r1 = (t + 768) >> 4;

    #pragma unroll 1
    for (int tile = blockIdx.x; tile < ntiles; tile += gridDim.x) {
        const int block0 = tile * MB;

        f32x4v acc[4];
        #pragma unroll
        for (int i = 0; i < 4; ++i) acc[i] = (f32x4v)0.f;

        // ---- prologue: chunk 0 into buffer 0 ----
        float4 pv0, pv1;
        pv0 = *(const float4*)(x + (size_t)min(block0 + r0, N - 1) * F + c0 * 4);
        if (t < 256)
            pv1 = *(const float4*)(x + (size_t)min(block0 + r1, N - 1) * F + c0 * 4);
        CVT_WRITE(0, r0, c0, pv0);
        if (t < 256) CVT_WRITE(0, r1, c0, pv1);

        #pragma unroll
        for (int c = 0; c < 4; ++c) {
            __syncthreads();          // buf[c&1] writes visible to all waves

            // issue next chunk's loads EARLY (consumed after the MFMAs)
            if (c < 3) {
                const int kb = (c + 1) * KC;
                pv0 = *(const float4*)(x + (size_t)min(block0 + r0, N - 1) * F + kb + c0 * 4);
                if (t < 256)
                    pv1 = *(const float4*)(x + (size_t)min(block0 + r1, N - 1) * F + kb + c0 * 4);
            }

            // MFMA burst on buf[c&1]; B frags from registers (u = c*2+sk)
            #pragma unroll
            for (int sk = 0; sk < 2; ++sk) {
                const int u = c * 2 + sk;
                #pragma unroll
                for (int mt = 0; mt < 4; ++mt) {
                    const int ao = (mt * 16 + l15) * XPAD + sk * 32 + quad * 8;
                    const bf16x8 ah = *(const bf16x8*)&xs_hi[c & 1][ao];
                    const bf16x8 al = *(const bf16x8*)&xs_lo[c & 1][ao];
                    f32x4v a = acc[mt];
                    a = __builtin_amdgcn_mfma_f32_16x16x32_bf16(ah, Bh[u], a, 0, 0, 0);
                    a = __builtin_amdgcn_mfma_f32_16x16x32_bf16(ah, Bl[u], a, 0, 0, 0);
                    a = __builtin_amdgcn_mfma_f32_16x16x32_bf16(al, Bh[u], a, 0, 0, 0);
                    acc[mt] = a;
                }
            }

            // convert + write next chunk into the other buffer (WAR-safe:
            // buf[nxt] last read in chunk c-1, all waves past top-of-c barrier)
            if (c < 3) {
                const int nb = (c & 1) ^ 1;
                CVT_WRITE(nb, r0, c0, pv0);
                if (t < 256) CVT_WRITE(nb, r1, c0, pv1);
            }
        }

        // epilogue: C layout col = lane&15, row = quad*4 + reg (m89-verified)
        #pragma unroll
        for (int mt = 0; mt < 4; ++mt) {
            #pragma unroll
            for (int r = 0; r < 4; ++r) {
                const int node = block0 + mt * 16 + quad * 4 + r;
                if (node < N)
                    dst[(size_t)node * H + col] = acc[mt][r] + bb;
            }
        }
    }
}

// ---------------------------------------------------------------------------
// Scan phase A/B/C: exclusive scan of padded (x4) per-node counts.
// scanA sums the 8 per-chunk histogram copies and emits merged counts.
// ---------------------------------------------------------------------------
__global__ __launch_bounds__(256) void scanA(
    const int* __restrict__ counts8, int* __restrict__ counts,
    int* __restrict__ offsets, int* __restrict__ bsum, int n)
{
    __shared__ int ps[256];
    const int t = threadIdx.x;
    const int i0 = blockIdx.x * SCB + t * 8;
    int loc[8];
    int s = 0;
    #pragma unroll
    for (int u = 0; u < 8; ++u) {
        int i = i0 + u;
        int c = 0;
        if (i < n) {
            #pragma unroll
            for (int p = 0; p < 8; ++p) c += counts8[(size_t)p * n + i];
            counts[i] = c;
            c = (c + 3) & ~3;
        }
        loc[u] = s; s += c;
    }
    ps[t] = s;
    __syncthreads();
    for (int off = 1; off < 256; off <<= 1) {
        int a = (t >= off) ? ps[t - off] : 0;
        __syncthreads();
        ps[t] += a;
        __syncthreads();
    }
    const int base = ps[t] - s;
    #pragma unroll
    for (int u = 0; u < 8; ++u) {
        int i = i0 + u;
        if (i < n) offsets[i] = base + loc[u];
    }
    if (t == 255) bsum[blockIdx.x] = ps[255];
}

__global__ void scanB(int* __restrict__ bsum, int nb)
{
    // single-wave shuffle exclusive scan (nb <= 64)
    const int t = threadIdx.x;
    int v = (t < nb) ? bsum[t] : 0;
    int inc = v;
    #pragma unroll
    for (int off = 1; off < 64; off <<= 1) {
        int u = __shfl_up(inc, off, 64);
        if (t >= off) inc += u;
    }
    if (t < nb) bsum[t] = inc - v;   // exclusive
}

__global__ __launch_bounds__(256) void scanC(
    const int* __restrict__ bsum, int* __restrict__ offsets,
    int* __restrict__ cursor, int n)
{
    const int i0 = blockIdx.x * SCB + threadIdx.x * 8;
    const int add = bsum[blockIdx.x];
    #pragma unroll
    for (int u = 0; u < 8; ++u) {
        int i = i0 + u;
        if (i < n) { int o = offsets[i] + add; offsets[i] = o; cursor[i] = o; }
    }
}

// ---------------------------------------------------------------------------
// Reorder edges into dst-node order, dst-range partitioned (R6-verified:
// epack/cursor lines single-XCD, WRITE_SIZE collapse).
// pack = src(16b) | seg(8b)<<16.
// ---------------------------------------------------------------------------
__global__ __launch_bounds__(256) void reorder_kernel(
    const int* __restrict__ ei, const int* __restrict__ batch,
    int* __restrict__ cursor, unsigned* __restrict__ epack,
    int E, int N, int nspan)
{
    const int p  = blockIdx.x & 7;
    const int ci = blockIdx.x >> 3;
    const int lo = p * nspan;
    const int hi = min(N, lo + nspan);
    const int e0 = ci * 1024 + threadIdx.x * 4;

    int d[4];
    if (e0 + 3 < E) {
        const int4 d4 = *(const int4*)(ei + E + e0);
        d[0] = d4.x; d[1] = d4.y; d[2] = d4.z; d[3] = d4.w;
    } else {
        #pragma unroll
        for (int u = 0; u < 4; ++u)
            d[u] = (e0 + u < E) ? ei[E + e0 + u] : -1;   // -1: never in span
    }

    #pragma unroll
    for (int u = 0; u < 4; ++u) {
        const int dst = min(max(d[u], 0), N - 1);
        if (d[u] >= 0 && dst >= lo && dst < hi) {
            int src = ei[e0 + u];
            src = min(max(src, 0), N - 1);
            int seg = batch[src];
            seg = min(max(seg, 0), NSEG - 1);
            const int pos = atomicAdd(&cursor[dst], 1);
            epack[pos] = (unsigned)src | ((unsigned)seg << 16);
        }
    }
}

// ---------------------------------------------------------------------------
// Score: persistent grid, one wave per dst node; q[dst] in registers across
// its edges; 4 edges in flight (16-lane groups, float4 k gathers, 4-step
// shuffle reduce).  Per-block LDS denom histogram flushed once into the
// block's XCD-private denom copy.
// ---------------------------------------------------------------------------
__global__ __launch_bounds__(256) void score_kernel(
    const float* __restrict__ q, const float* __restrict__ k,
    const unsigned* __restrict__ epack,
    const int* __restrict__ offsets, const int* __restrict__ counts,
    float* __restrict__ exps, float* __restrict__ denom8, int N)
{
    __shared__ float sden[NSEG];
    const int t = threadIdx.x;
    sden[t] = 0.f;
    __syncthreads();

    const int lane16 = t & 15;
    const int grp    = (t >> 4) & 3;
    const int wave   = t >> 6;
    const int nwaves = gridDim.x * 4;

    const float4* q4 = (const float4*)q;
    const float4* k4 = (const float4*)k;

    for (int n = blockIdx.x * 4 + wave; n < N; n += nwaves) {
        const int off = offsets[n];
        const int cnt = counts[n];
        if (cnt == 0) continue;
        const float4 qv = q4[(size_t)n * 16 + lane16];
        for (int i = grp; i < cnt; i += 4) {
            const int pos = off + i;
            const unsigned p = epack[pos];
            const int src = p & 0xFFFF;
            const float4 kv = k4[(size_t)src * 16 + lane16];
            float d = kv.x * qv.x + kv.y * qv.y + kv.z * qv.z + kv.w * qv.w;
            d += __shfl_xor(d, 1, 64);
            d += __shfl_xor(d, 2, 64);
            d += __shfl_xor(d, 4, 64);
            d += __shfl_xor(d, 8, 64);
            if (lane16 == 0) {
                float ex = __expf(d * 0.125f);
                exps[pos] = ex;
                atomicAdd(&sden[(p >> 16) & 255], ex);
            }
        }
    }
    __syncthreads();
    float ds = sden[t];
    if (ds != 0.f) atomicAdd(&denom8[(blockIdx.x & 7) * NSEG + t], ds);
}

// ---------------------------------------------------------------------------
// Accumulate: one wave per dst node, lane = feature, register accumulator,
// zero atomics.  LDS reciprocal table built by summing the 8 denom copies.
// ---------------------------------------------------------------------------
__global__ __launch_bounds__(256) void accum_kernel(
    const float* __restrict__ v, const float* __restrict__ exps,
    const unsigned* __restrict__ epack,
    const int* __restrict__ offsets, const int* __restrict__ counts,
    const float* __restrict__ denom8, float* __restrict__ out, int N)
{
    __shared__ float rden[NSEG];
    const int t = threadIdx.x;
    {
        float dsum = 0.f;
        #pragma unroll
        for (int p = 0; p < 8; ++p) dsum += denom8[p * NSEG + t];
        rden[t] = 1.0f / (dsum + 1e-6f);
    }
    __syncthreads();

    const int lane = t & 63;
    const int wave = t >> 6;
    const int n = blockIdx.x * 4 + wave;
    if (n >= N) return;

    const int off = offsets[n];
    const int cnt = counts[n];

    float acc = 0.f;
    int i = 0;
    for (; i + 8 <= cnt; i += 8) {
        const uint4  pa = *(const uint4*)(epack + off + i);
        const uint4  pb = *(const uint4*)(epack + off + i + 4);
        const float4 ea = *(const float4*)(exps + off + i);
        const float4 eb = *(const float4*)(exps + off + i + 4);
        const float v0 = v[(size_t)(pa.x & 0xFFFF) * H + lane];
        const float v1 = v[(size_t)(pa.y & 0xFFFF) * H + lane];
        const float v2 = v[(size_t)(pa.z & 0xFFFF) * H + lane];
        const float v3 = v[(size_t)(pa.w & 0xFFFF) * H + lane];
        const float v4_ = v[(size_t)(pb.x & 0xFFFF) * H + lane];
        const float v5 = v[(size_t)(pb.y & 0xFFFF) * H + lane];
        const float v6 = v[(size_t)(pb.z & 0xFFFF) * H + lane];
        const float v7 = v[(size_t)(pb.w & 0xFFFF) * H + lane];
        acc = fmaf(v0, ea.x * rden[(pa.x >> 16) & 255], acc);
        acc = fmaf(v1, ea.y * rden[(pa.y >> 16) & 255], acc);
        acc = fmaf(v2, ea.z * rden[(pa.z >> 16) & 255], acc);
        acc = fmaf(v3, ea.w * rden[(pa.w >> 16) & 255], acc);
        acc = fmaf(v4_, eb.x * rden[(pb.x >> 16) & 255], acc);
        acc = fmaf(v5, eb.y * rden[(pb.y >> 16) & 255], acc);
        acc = fmaf(v6, eb.z * rden[(pb.z >> 16) & 255], acc);
        acc = fmaf(v7, eb.w * rden[(pb.w >> 16) & 255], acc);
    }
    for (; i + 4 <= cnt; i += 4) {
        const uint4  pp = *(const uint4*)(epack + off + i);
        const float4 ee = *(const float4*)(exps + off + i);
        const float v0 = v[(size_t)(pp.x & 0xFFFF) * H + lane];
        const float v1 = v[(size_t)(pp.y & 0xFFFF) * H + lane];
        const float v2 = v[(size_t)(pp.z & 0xFFFF) * H + lane];
        const float v3 = v[(size_t)(pp.w & 0xFFFF) * H + lane];
        acc = fmaf(v0, ee.x * rden[(pp.x >> 16) & 255], acc);
        acc = fmaf(v1, ee.y * rden[(pp.y >> 16) & 255], acc);
        acc = fmaf(v2, ee.z * rden[(pp.z >> 16) & 255], acc);
        acc = fmaf(v3, ee.w * rden[(pp.w >> 16) & 255], acc);
    }
    for (; i < cnt; ++i) {
        const unsigned p = epack[off + i];
        acc = fmaf(v[(size_t)(p & 0xFFFF) * H + lane],
                   exps[off + i] * rden[(p >> 16) & 255], acc);
    }
    out[(size_t)n * H + lane] = acc;
}

extern "C" void kernel_launch(void* const* d_in, const int* in_sizes, int n_in,
                              void* d_out, int out_size, void* d_ws, size_t ws_size,
                              hipStream_t stream)
{
    const float* x   = (const float*)d_in[0];
    const float* Wq  = (const float*)d_in[1];
    const float* bq  = (const float*)d_in[2];
    const float* Wk  = (const float*)d_in[3];
    const float* bk  = (const float*)d_in[4];
    const float* Wv  = (const float*)d_in[5];
    const float* bv  = (const float*)d_in[6];
    const int* ei    = (const int*)d_in[7];
    const int* batch = (const int*)d_in[8];

    const int N = in_sizes[8];        // 50000
    const int E = in_sizes[7] / 2;    // 800000
    const int EP = E + 3 * N + 16;    // padded edge-slot capacity

    float*    q       = (float*)d_ws;
    float*    k       = q + (size_t)N * H;
    float*    v       = k + (size_t)N * H;
    float*    exps    = v + (size_t)N * H;
    unsigned* epack   = (unsigned*)(exps + EP);
    int*      counts  = (int*)(epack + EP);
    int*      offsets = counts + N;
    int*      cursor  = offsets + N;
    int*      bsum    = cursor + N;
    float*    denom8  = (float*)(bsum + 64);
    int*      counts8 = (int*)(denom8 + 8 * NSEG);   // 8N ints

    hipMemsetAsync(denom8, 0, 8 * NSEG * sizeof(float), stream);

    const int NT    = (N + MB - 1) / MB;     // 782 row tiles
    const int NC    = (E + 1023) / 1024;     // 782 edge chunks
    const int nspan = (N + 7) / 8;           // dst-range span per XCD class
    const int NBSC  = (N + SCB - 1) / SCB;   // 25 scan blocks

    hist8_kernel<<<64, 1024, 0, stream>>>(ei, counts8, N, E, nspan);

    qkv_mfma<<<256, 768, 0, stream>>>(
        x, Wq, Wk, Wv, bq, bk, bv, q, k, v, N, NT);

    scanA<<<NBSC, 256, 0, stream>>>(counts8, counts, offsets, bsum, N);
    scanB<<<1, 64, 0, stream>>>(bsum, NBSC);
    scanC<<<NBSC, 256, 0, stream>>>(bsum, offsets, cursor, N);

    reorder_kernel<<<8 * NC, 256, 0, stream>>>(
        ei, batch, cursor, epack, E, N, nspan);

    score_kernel<<<2048, 256, 0, stream>>>(
        q, k, epack, offsets, counts, exps, denom8, N);

    accum_kernel<<<(N + 3) / 4, 256, 0, stream>>>(
        v, exps, epack, offsets, counts, denom8, (float*)d_out, N);
}